// Round 3
// baseline (280.684 us; speedup 1.0000x reference)
//
#include <hip/hip_runtime.h>
#include <math.h>

// ===========================================================================
// ROUND-3 MEASUREMENT PROBE: every kernel repeats its full body REPS=3 times
// (idempotent re-execution; rep-boundary __syncthreads protects LDS reuse).
// dur_us_new ~= overhead + 3*kernels  ->  kernel share = (new - old)/2.
// Kernels >= ~14us become visible in the rocprof top-5 at 3x duration.
// ===========================================================================
#define REPS 3

#define BB 8
#define LQ 2048
#define DD 300
#define HHH 150
#define NROWS (BB * LQ)

#define KP 168          // row stride (elems) for AhB / Qg / W rows (336 B)
#define QTS 72          // QhT q-stride (144 B)
#define WCE 27136       // padded elems per W chunk (54,272 B; multiple of 1024)
#define SLAB_B 46080    // per-(b,qt) slab bytes (45 KiB, 45 x 1024-B chunks)
#define SLAB_E 23040    // slab elems; used: Qg 64x168=10752 | QhT @11008 160x72
#define QHT_OFF_E 11008

typedef __bf16 bf16x8 __attribute__((ext_vector_type(8)));
typedef __bf16 bf16x4 __attribute__((ext_vector_type(4)));
typedef float f32x16 __attribute__((ext_vector_type(16)));

__device__ __forceinline__ void gl_lds16(const void* g, void* l) {
    __builtin_amdgcn_global_load_lds(
        (const __attribute__((address_space(1))) void*)g,
        (__attribute__((address_space(3))) void*)l,
        16, 0, 0);
}
// flat async global->LDS copy, 4-wave (256-thr) blocks
__device__ __forceinline__ void stage_flat(const void* g, void* l, int bytes,
                                           int w, int lane) {
    for (int ofs = w * 1024; ofs < bytes; ofs += 4096)
        gl_lds16((const char*)g + ofs + lane * 16, (char*)l + ofs);
}
// flat async global->LDS copy, 8-wave (512-thr) blocks
__device__ __forceinline__ void stage_flat8(const void* g, void* l, int bytes,
                                            int w, int lane) {
    for (int ofs = w * 1024; ofs < bytes; ofs += 8192)
        gl_lds16((const char*)g + ofs + lane * 16, (char*)l + ofs);
}
__device__ __forceinline__ f32x16 z16() {
    f32x16 v;
#pragma unroll
    for (int i = 0; i < 16; i++) v[i] = 0.f;
    return v;
}
__device__ __forceinline__ bf16x8 cvt8(float4 u, float4 v) {
    return (bf16x8){(__bf16)u.x, (__bf16)u.y, (__bf16)u.z, (__bf16)u.w,
                    (__bf16)v.x, (__bf16)v.y, (__bf16)v.z, (__bf16)v.w};
}
// pack two f32 -> one u32 of 2 bf16 (no builtin on gfx950; m240)
__device__ __forceinline__ unsigned pk2(float lo, float hi) {
    unsigned d;
    asm("v_cvt_pk_bf16_f32 %0, %1, %2" : "=v"(d) : "v"(lo), "v"(hi));
    return d;
}
// swap a.high-lanes <-> b.low-lanes (v_permlane32_swap_b32 modifies both regs)
__device__ __forceinline__ void pl32(unsigned& a, unsigned& b) {
    asm("v_permlane32_swap_b32 %0, %1" : "+v"(a), "+v"(b));
}
__device__ __forceinline__ bf16x8 mk8(unsigned a, unsigned b, unsigned c, unsigned d) {
    union { unsigned u[4]; bf16x8 v; } x;
    x.u[0] = a; x.u[1] = b; x.u[2] = c; x.u[3] = d;
    return x.v;
}

// ---------------------------------------------------------------------------
// Weight conversion. z=0/1: WiC/WuC [2 chunks][160h][168k]; z=2: WgT; z=3: Wt12.
// ---------------------------------------------------------------------------
__global__ __launch_bounds__(256) void convert_weights(
    const float* __restrict__ Wi, const float* __restrict__ Wu,
    const float* __restrict__ Wg, const float* __restrict__ Wt,
    __bf16* __restrict__ WiC, __bf16* __restrict__ WuC,
    __bf16* __restrict__ WgT, __bf16* __restrict__ Wt12)
{
    const int z = blockIdx.y;
    const int i = blockIdx.x * 256 + threadIdx.x;
    for (int rep = 0; rep < REPS; rep++) {
        asm volatile("" ::: "memory");   // defeat cross-rep store elision
        if (z < 2) {
            if (i < 2 * WCE) {
                int c = i / WCE, rem = i - c * WCE;
                float v = 0.f;
                if (rem < 160 * KP) {
                    int h = rem / KP, kc = rem - h * KP;
                    int d = c * 160 + kc;
                    if (kc < 160 && d < DD && h < HHH) v = (z ? Wu : Wi)[(size_t)d * HHH + h];
                }
                (z ? WuC : WiC)[i] = (__bf16)v;
            }
        } else if (z == 2) {
            if (i < WCE) {
                float v = 0.f;
                if (i < 160 * KP) {
                    int h = i / KP, kc = i - h * KP;
                    if (kc < HHH && h < HHH) v = Wg[(size_t)kc * HHH + h];
                }
                WgT[i] = (__bf16)v;
            }
        } else {
            if (i < 2 * 160 * KP) {
                int c = i / (160 * KP), rem = i - c * (160 * KP);
                int h = rem / KP, kc = rem - h * KP;
                float v = (kc < HHH && h < HHH) ? Wt[(size_t)(c * HHH + kc) * HHH + h] : 0.f;
                Wt12[i] = (__bf16)v;
            }
        }
    }
}

// ---------------------------------------------------------------------------
// gatep v3 (+REPS probe): 512 thr / 8 waves. Wave (wm = w&3, wn = w>>2):
// rows wm*32..+31, h-tiles tof..tof+tn-1 (3/2 ragged split).
// z=1: Ah = gate(A) -> AhB.  z=0: Qh on-chip -> slab Qg + slab QhT.
// ---------------------------------------------------------------------------
__global__ __launch_bounds__(512, 2) void gatep(
    const float* __restrict__ Q, const float* __restrict__ A,
    const __bf16* __restrict__ WiC, const __bf16* __restrict__ WuC,
    const __bf16* __restrict__ WgT,
    const float* __restrict__ bi, const float* __restrict__ bu,
    const float* __restrict__ bg,
    __bf16* __restrict__ AhB, __bf16* __restrict__ Slab)
{
    __shared__ __align__(16) __bf16 WB[2][WCE];      // 108,544 B
    __shared__ __align__(16) __bf16 QhA[128 * KP];   //  43,008 B
    const int tid = threadIdx.x;
    const int w = tid >> 6, lane = tid & 63;
    const int m32 = lane & 31, half = lane >> 5;
    const int wm = w & 3, wn = w >> 2;
    const int tof = wn ? 3 : 0, tn = wn ? 2 : 3;
    const int z = blockIdx.y;
    const int r0 = blockIdx.x * 128;
    const float* X = z ? A : Q;

    for (int rep = 0; rep < REPS; rep++) {
    if (rep) __syncthreads();   // protect WB/QhA from prior rep's tail reads

    stage_flat8(WiC, WB[0], 54272, w, lane);   // async; overlaps frag loads

    // ---- chunk-0 A-fragments straight from global (fp32 -> bf16) ----
    const float* xrow = X + (size_t)(r0 + wm * 32 + m32) * DD + half * 8;
    bf16x8 af0[10], af1[10];
#pragma unroll
    for (int ks = 0; ks < 10; ks++) {
        float4 u = *(const float4*)(xrow + ks * 16);
        float4 v = *(const float4*)(xrow + ks * 16 + 4);
        af0[ks] = cvt8(u, v);
    }

    f32x16 ai[3], au[3];
#pragma unroll
    for (int t = 0; t < 3; t++) { ai[t] = z16(); au[t] = z16(); }

    __syncthreads();                                   // WB0 = Wi-c0 ready
    stage_flat8(WuC, WB[1], 54272, w, lane);

    // chunk-1 fragments (hidden under ai-c0 MFMA phase)
#pragma unroll
    for (int ks = 0; ks < 8; ks++) {
        float4 u = *(const float4*)(xrow + 160 + ks * 16);
        float4 v = *(const float4*)(xrow + 160 + ks * 16 + 4);
        af1[ks] = cvt8(u, v);
    }
    {   // ks=8 tail: k>=300 masked (weights are zero there anyway)
        float4 u = *(const float4*)(xrow + 288);
        float4 v = (half == 0) ? *(const float4*)(xrow + 292) : (float4){0.f, 0.f, 0.f, 0.f};
        af1[8] = cvt8(u, v);
        af1[9] = (bf16x8){(__bf16)0.f, (__bf16)0.f, (__bf16)0.f, (__bf16)0.f,
                          (__bf16)0.f, (__bf16)0.f, (__bf16)0.f, (__bf16)0.f};
    }

    for (int ks = 0; ks < 10; ks++)
#pragma unroll
        for (int ti = 0; ti < 3; ti++)
            if (ti < tn)
                ai[ti] = __builtin_amdgcn_mfma_f32_32x32x16_bf16(
                    af0[ks], *(const bf16x8*)(WB[0] + ((tof + ti) * 32 + m32) * KP + ks * 16 + half * 8),
                    ai[ti], 0, 0, 0);
    __syncthreads();                                   // WB1 = Wu-c0 ready
    stage_flat8(WiC + WCE, WB[0], 54272, w, lane);
    for (int ks = 0; ks < 10; ks++)
#pragma unroll
        for (int ti = 0; ti < 3; ti++)
            if (ti < tn)
                au[ti] = __builtin_amdgcn_mfma_f32_32x32x16_bf16(
                    af0[ks], *(const bf16x8*)(WB[1] + ((tof + ti) * 32 + m32) * KP + ks * 16 + half * 8),
                    au[ti], 0, 0, 0);
    __syncthreads();                                   // WB0 = Wi-c1 ready
    stage_flat8(WuC + WCE, WB[1], 54272, w, lane);
    for (int ks = 0; ks < 10; ks++)
#pragma unroll
        for (int ti = 0; ti < 3; ti++)
            if (ti < tn)
                ai[ti] = __builtin_amdgcn_mfma_f32_32x32x16_bf16(
                    af1[ks], *(const bf16x8*)(WB[0] + ((tof + ti) * 32 + m32) * KP + ks * 16 + half * 8),
                    ai[ti], 0, 0, 0);
    __syncthreads();                                   // WB1 = Wu-c1 ready
    if (z == 0) stage_flat8(WgT, WB[0], 54272, w, lane);  // prefetch Wg
    for (int ks = 0; ks < 10; ks++)
#pragma unroll
        for (int ti = 0; ti < 3; ti++)
            if (ti < tn)
                au[ti] = __builtin_amdgcn_mfma_f32_32x32x16_bf16(
                    af1[ks], *(const bf16x8*)(WB[1] + ((tof + ti) * 32 + m32) * KP + ks * 16 + half * 8),
                    au[ti], 0, 0, 0);

    // ---- gate epilogue ----
#pragma unroll
    for (int ti = 0; ti < 3; ti++) {
        if (ti >= tn) continue;
        int h = (tof + ti) * 32 + m32;
        int hc = h < HHH ? h : 0;
        float bih = bi[hc], buh = bu[hc];
#pragma unroll
        for (int r = 0; r < 16; r++) {
            float v = 0.f;
            if (h < HHH) {
                float xi = ai[ti][r] + bih, xu = au[ti][r] + buh;
                float s = 1.f / (1.f + __expf(-xi));
                float tt = 1.f - 2.f / (1.f + __expf(2.f * xu));
                v = s * tt;
            }
            ai[ti][r] = v;
        }
    }

    if (z) {  // A-side: write AhB
#pragma unroll
        for (int ti = 0; ti < 3; ti++) {
            if (ti >= tn) continue;
            int h = (tof + ti) * 32 + m32;
#pragma unroll
            for (int r = 0; r < 16; r++) {
                int rowp = (r & 3) + 8 * (r >> 2) + 4 * half;
                AhB[(size_t)(r0 + wm * 32 + rowp) * KP + h] = (__bf16)ai[ti][r];
            }
        }
        continue;   // next rep
    }

    // ---- Q-side: Qh -> LDS (rows shared across wn halves) ----
#pragma unroll
    for (int ti = 0; ti < 3; ti++) {
        if (ti >= tn) continue;
        int h = (tof + ti) * 32 + m32;
#pragma unroll
        for (int r = 0; r < 16; r++) {
            int rowp = (r & 3) + 8 * (r >> 2) + 4 * half;
            QhA[(wm * 32 + rowp) * KP + h] = (__bf16)ai[ti][r];
        }
    }
    __syncthreads();   // QhA visible block-wide; Wg in WB0 ready

    bf16x8 afq[10];
#pragma unroll
    for (int ks = 0; ks < 10; ks++)
        afq[ks] = *(const bf16x8*)(QhA + (wm * 32 + m32) * KP + ks * 16 + half * 8);

    f32x16 qg[3];
#pragma unroll
    for (int t = 0; t < 3; t++) qg[t] = z16();
    for (int ks = 0; ks < 10; ks++)
#pragma unroll
        for (int ti = 0; ti < 3; ti++)
            if (ti < tn)
                qg[ti] = __builtin_amdgcn_mfma_f32_32x32x16_bf16(
                    afq[ks], *(const bf16x8*)(WB[0] + ((tof + ti) * 32 + m32) * KP + ks * 16 + half * 8),
                    qg[ti], 0, 0, 0);

    const int b = r0 >> 11, qt0 = (r0 & 2047) >> 6;
#pragma unroll
    for (int ti = 0; ti < 3; ti++) {
        if (ti >= tn) continue;
        int h = (tof + ti) * 32 + m32;
        int hc = h < HHH ? h : 0;
        float bgh = bg[hc];
#pragma unroll
        for (int r = 0; r < 16; r++) {
            int rowp = (r & 3) + 8 * (r >> 2) + 4 * half;
            int q = (r0 & 2047) + wm * 32 + rowp;
            float v = (h < HHH) ? (qg[ti][r] + bgh) : 0.f;
            Slab[(size_t)(b * 32 + (q >> 6)) * SLAB_E + (q & 63) * KP + h] = (__bf16)v;
        }
    }

    // QhT transpose-scatter (512 threads)
    {
        const int jl = tid & 63, tile = (tid >> 6) & 1, hgrp = tid >> 7;
        for (int hseg = hgrp; hseg < 20; hseg += 4) {
            bf16x8 vv = *(const bf16x8*)(QhA + (tile * 64 + jl) * KP + hseg * 8);
            __bf16* dst = Slab + (size_t)(b * 32 + qt0 + tile) * SLAB_E + QHT_OFF_E + jl;
#pragma unroll
            for (int e = 0; e < 8; e++)
                dst[(hseg * 8 + e) * QTS] = vv[e];
        }
    }
    }  // rep
}

// ---------------------------------------------------------------------------
// attn v9 (+REPS probe): T12 in-register P + 3-deep counted-vmcnt pipeline.
// ---------------------------------------------------------------------------
__global__ __launch_bounds__(512, 2) void attn_mfma(
    const __bf16* __restrict__ Slab, const __bf16* __restrict__ AhB,
    __bf16* __restrict__ O, float* __restrict__ L)
{
    __shared__ __align__(16) __bf16 Buf[3][SLAB_E];   // 138,240 B
    const int tid = threadIdx.x;
    const int w = tid >> 6, lane = tid & 63;
    const int m32 = lane & 31, half = lane >> 5;
    const int grp = blockIdx.x;            // 0..31 = b*4 + qp
    const int b = grp >> 2, qp = grp & 3;
    const int a0 = blockIdx.y * 256;

    const char* slabBase = (const char*)Slab + (size_t)(b * 32 + qp * 8) * SLAB_B;
    const __bf16* arow = AhB + (size_t)(b * LQ + a0 + w * 32 + m32) * KP + half * 8;

    for (int rep = 0; rep < REPS; rep++) {
    if (rep) __syncthreads();   // protect Buf from prior rep's qt==7 reads

    stage_flat8(slabBase, Buf[0], SLAB_B, w, lane);           // t0: 5-6 loads
    __builtin_amdgcn_sched_barrier(0);

    // A-fragments from global (pinned between the two stage batches so the
    // prologue vmcnt(15) counts exactly: t0(<=6) + af(10) + t1(<=6))
    bf16x8 af[10];
#pragma unroll
    for (int ks = 0; ks < 10; ks++)
        af[ks] = *(const bf16x8*)(arow + ks * 16);
    __builtin_amdgcn_sched_barrier(0);

    stage_flat8(slabBase + SLAB_B, Buf[1], SLAB_B, w, lane);  // t1
    __builtin_amdgcn_sched_barrier(0);
    asm volatile("s_waitcnt vmcnt(15)" ::: "memory");          // t0 landed
    __builtin_amdgcn_sched_barrier(0);
    __builtin_amdgcn_s_barrier();
    __builtin_amdgcn_sched_barrier(0);

    float lsum = 0.f;
    f32x16 acc[5];
#pragma unroll
    for (int t = 0; t < 5; t++) acc[t] = z16();

    for (int qt = 0; qt < 8; qt++) {
        if (qt < 6)
            stage_flat8(slabBase + (size_t)(qt + 2) * SLAB_B, Buf[(qt + 2) % 3],
                        SLAB_B, w, lane);
        const __bf16* Bq = Buf[qt % 3];
        const __bf16* Bv = Bq + QHT_OFF_E;

        // S^T = Qg(64q rows) x Ah(32a cols), K=160 -> two 32x32 tiles
        f32x16 s0 = z16(), s1 = z16();
        __builtin_amdgcn_s_setprio(1);
        for (int ks = 0; ks < 10; ks++) {
            bf16x8 b0 = *(const bf16x8*)(Bq + m32 * KP + ks * 16 + half * 8);
            bf16x8 b1 = *(const bf16x8*)(Bq + (32 + m32) * KP + ks * 16 + half * 8);
            s0 = __builtin_amdgcn_mfma_f32_32x32x16_bf16(b0, af[ks], s0, 0, 0, 0);
            s1 = __builtin_amdgcn_mfma_f32_32x32x16_bf16(b1, af[ks], s1, 0, 0, 0);
        }
        __builtin_amdgcn_s_setprio(0);

        // P = exp(S) in-register; accumulate l (lane's column a = m32)
#pragma unroll
        for (int r = 0; r < 16; r++) { s0[r] = __expf(s0[r]); lsum += s0[r]; }
#pragma unroll
        for (int r = 0; r < 16; r++) { s1[r] = __expf(s1[r]); lsum += s1[r]; }

        // Build PV B-frags in-register (T12): cvt_pk + permlane32_swap.
        bf16x8 pf[4];
        {
            unsigned w01 = pk2(s0[0], s0[1]),   w45 = pk2(s0[4], s0[5]);
            unsigned w23 = pk2(s0[2], s0[3]),   w67 = pk2(s0[6], s0[7]);
            pl32(w01, w45); pl32(w23, w67);
            pf[0] = mk8(w01, w23, w45, w67);
            unsigned x01 = pk2(s0[8], s0[9]),   x45 = pk2(s0[12], s0[13]);
            unsigned x23 = pk2(s0[10], s0[11]), x67 = pk2(s0[14], s0[15]);
            pl32(x01, x45); pl32(x23, x67);
            pf[1] = mk8(x01, x23, x45, x67);
        }
        {
            unsigned w01 = pk2(s1[0], s1[1]),   w45 = pk2(s1[4], s1[5]);
            unsigned w23 = pk2(s1[2], s1[3]),   w67 = pk2(s1[6], s1[7]);
            pl32(w01, w45); pl32(w23, w67);
            pf[2] = mk8(w01, w23, w45, w67);
            unsigned x01 = pk2(s1[8], s1[9]),   x45 = pk2(s1[12], s1[13]);
            unsigned x23 = pk2(s1[10], s1[11]), x67 = pk2(s1[14], s1[15]);
            pl32(x01, x45); pl32(x23, x67);
            pf[3] = mk8(x01, x23, x45, x67);
        }

        // O^T: acc[t] = QhT(h-rows) x P(a-cols) -> O[a=m32][h = t*32 + rowp]
        __builtin_amdgcn_s_setprio(1);
#pragma unroll
        for (int kk = 0; kk < 4; kk++)
#pragma unroll
            for (int t = 0; t < 5; t++)
                acc[t] = __builtin_amdgcn_mfma_f32_32x32x16_bf16(
                    *(const bf16x8*)(Bv + (t * 32 + m32) * QTS + kk * 16 + half * 8),
                    pf[kk], acc[t], 0, 0, 0);
        __builtin_amdgcn_s_setprio(0);

        if (qt < 7) {
            __builtin_amdgcn_sched_barrier(0);
            if (qt < 6) asm volatile("s_waitcnt vmcnt(5)" ::: "memory");
            else        asm volatile("s_waitcnt vmcnt(0)" ::: "memory");
            __builtin_amdgcn_sched_barrier(0);
            __builtin_amdgcn_s_barrier();
            __builtin_amdgcn_sched_barrier(0);
        }
    }

    // l: this lane has half the q's of column a=m32; partner lane^32 the rest
    float lt = lsum + __shfl_xor(lsum, 32, 64);

    // O store: row a = w*32 + m32; h = t*32 + rq*8 + half*4 + j (contiguous 4)
    __bf16* Ob = O + ((size_t)qp * NROWS + b * LQ + a0 + w * 32) * 160;
#pragma unroll
    for (int t = 0; t < 5; t++)
#pragma unroll
        for (int rq = 0; rq < 4; rq++) {
            bf16x4 hv = {(__bf16)acc[t][rq * 4 + 0], (__bf16)acc[t][rq * 4 + 1],
                         (__bf16)acc[t][rq * 4 + 2], (__bf16)acc[t][rq * 4 + 3]};
            *(bf16x4*)(Ob + (size_t)m32 * 160 + t * 32 + rq * 8 + half * 4) = hv;
        }
    if (half == 0)
        L[(size_t)qp * NROWS + b * LQ + a0 + w * 32 + m32] = lt;
    }  // rep
}

// ---------------------------------------------------------------------------
// final (+REPS probe): Hm = (sum of 4 O partials)/(sum l);
// Out = relu([Ah,Hm]@Wt+bt). Wt staged in LDS (WtS).
// ---------------------------------------------------------------------------
__global__ __launch_bounds__(256, 1) void final_mfma(
    const __bf16* __restrict__ AhB, const __bf16* __restrict__ O,
    const float* __restrict__ L, const __bf16* __restrict__ Wt12,
    const float* __restrict__ bt, float* __restrict__ Out)
{
    __shared__ __align__(16) __bf16 AS[64 * KP];          // 21504 B
    __shared__ __align__(16) __bf16 HS[64 * KP];          // 21504 B
    __shared__ __align__(16) __bf16 WtS[2 * 160 * KP];    // 107520 B
    const int tid = threadIdx.x;
    const int w = tid >> 6, lane = tid & 63;
    const int m32 = lane & 31, half = lane >> 5;
    const int r0 = blockIdx.x * 64;

    for (int rep = 0; rep < REPS; rep++) {
    if (rep) __syncthreads();   // protect AS/HS/WtS from prior rep's reads

    stage_flat(AhB + (size_t)r0 * KP, AS, 21504, w, lane);
    stage_flat(Wt12, WtS, 107520, w, lane);

    // combine 4 partials -> HS
    {
        int rhat = tid >> 2, qq = tid & 3;
        int grow = r0 + rhat;
        float inv = 1.f / (L[grow] + L[NROWS + grow] + L[2 * NROWS + grow] + L[3 * NROWS + grow]);
#pragma unroll
        for (int k = 0; k < 5; k++) {
            float sum[8];
#pragma unroll
            for (int j = 0; j < 8; j++) sum[j] = 0.f;
#pragma unroll
            for (int p = 0; p < 4; p++) {
                bf16x8 x = *(const bf16x8*)(O + ((size_t)p * NROWS + grow) * 160 + qq * 40 + k * 8);
#pragma unroll
                for (int j = 0; j < 8; j++) sum[j] += (float)x[j];
            }
            bf16x8 hv;
#pragma unroll
            for (int j = 0; j < 8; j++) hv[j] = (__bf16)(sum[j] * inv);
            *(bf16x8*)(HS + rhat * KP + qq * 40 + k * 8) = hv;
        }
    }
    __syncthreads();

    const int m = w & 1, th = w >> 1;
    const int tbase = th ? 3 : 0, tn = th ? 2 : 3;
    f32x16 acc[3];
#pragma unroll
    for (int i = 0; i < 3; i++) acc[i] = z16();

    for (int ch = 0; ch < 2; ch++) {
        const __bf16* src = ch ? HS : AS;
        for (int ks = 0; ks < 10; ks++) {
            bf16x8 af = *(const bf16x8*)(src + (m * 32 + m32) * KP + ks * 16 + half * 8);
#pragma unroll
            for (int ti = 0; ti < 3; ti++) {
                if (ti < tn) {
                    int t = tbase + ti;
                    acc[ti] = __builtin_amdgcn_mfma_f32_32x32x16_bf16(
                        af, *(const bf16x8*)(WtS + (ch * 160 + t * 32 + m32) * KP + ks * 16 + half * 8),
                        acc[ti], 0, 0, 0);
                }
            }
        }
    }

#pragma unroll
    for (int ti = 0; ti < 3; ti++) {
        if (ti < tn) {
            int t = tbase + ti;
            int h = t * 32 + m32;
            if (h < HHH) {
                float bth = bt[h];
#pragma unroll
                for (int r = 0; r < 16; r++) {
                    int rowp = (r & 3) + 8 * (r >> 2) + 4 * half;
                    float v = acc[ti][r] + bth;
                    Out[(size_t)(r0 + m * 32 + rowp) * HHH + h] = v > 0.f ? v : 0.f;
                }
            }
        }
    }
    }  // rep
}

// ---------------------------------------------------------------------------
extern "C" void kernel_launch(void* const* d_in, const int* in_sizes, int n_in,
                              void* d_out, int out_size, void* d_ws, size_t ws_size,
                              hipStream_t stream)
{
    const float* Q  = (const float*)d_in[0];
    const float* A  = (const float*)d_in[1];
    const float* Wi = (const float*)d_in[2];
    const float* Wu = (const float*)d_in[3];
    const float* Wg = (const float*)d_in[4];
    const float* Wt = (const float*)d_in[5];
    const float* bi = (const float*)d_in[6];
    const float* bu = (const float*)d_in[7];
    const float* bg = (const float*)d_in[8];
    const float* bt = (const float*)d_in[9];
    float* out = (float*)d_out;

    char* ws = (char*)d_ws;
    __bf16* Slab = (__bf16*)(ws);                    // 11,796,480 B (256 x 46,080)
    __bf16* AhB  = (__bf16*)(ws + 11796480);         //  5,505,024 B
    __bf16* Op   = (__bf16*)(ws + 17301504);         // 20,971,520 B (4 partials)
    float*  Lp   = (float*) (ws + 38273024);         //    262,144 B (4 partials)
    __bf16* WiC  = (__bf16*)(ws + 38535168);         //    108,544 B
    __bf16* WuC  = (__bf16*)(ws + 38643712);         //    108,544 B
    __bf16* WgT  = (__bf16*)(ws + 38752256);         //     54,272 B
    __bf16* Wt12 = (__bf16*)(ws + 38806528);         //    107,520 B

    convert_weights<<<dim3(212, 4), 256, 0, stream>>>(Wi, Wu, Wg, Wt,
                                                      WiC, WuC, WgT, Wt12);
    gatep<<<dim3(NROWS / 128, 2), 512, 0, stream>>>(Q, A, WiC, WuC, WgT,
                                                    bi, bu, bg, AhB, Slab);
    attn_mfma<<<dim3(32, 8), 512, 0, stream>>>(Slab, AhB, Op, Lp);
    final_mfma<<<NROWS / 64, 256, 0, stream>>>(AhB, Op, Lp, Wt12, bt, out);
}

// Round 4
// 209.501 us; speedup vs baseline: 1.3398x; 1.3398x over previous
//
#include <hip/hip_runtime.h>
#include <math.h>

#define BB 8
#define LQ 2048
#define DD 300
#define HHH 150
#define NROWS (BB * LQ)

#define KP 168          // row stride (elems) for AhB / Qg / QhA / Wt rows (336 B)
#define QTS 72          // QhT q-stride (144 B)
#define KQ 88           // W quarter-chunk row stride (elems, 176 B, 16B-aligned)
#define WCQ 14336       // elems per W quarter-chunk buffer (28,672 B)
#define STG_B 28160     // staged bytes per quarter chunk (160*88*2)
#define SLAB_B 46080    // per-(b,qt) slab bytes (45 KiB)
#define SLAB_E 23040    // slab elems; used: Qg 64x168 | QhT @11008 160x72
#define QHT_OFF_E 11008

typedef __bf16 bf16x8 __attribute__((ext_vector_type(8)));
typedef __bf16 bf16x4 __attribute__((ext_vector_type(4)));
typedef float f32x16 __attribute__((ext_vector_type(16)));

__device__ __forceinline__ void gl_lds16(const void* g, void* l) {
    __builtin_amdgcn_global_load_lds(
        (const __attribute__((address_space(1))) void*)g,
        (__attribute__((address_space(3))) void*)l,
        16, 0, 0);
}
// flat async global->LDS copy, 4-wave (256-thr) blocks
__device__ __forceinline__ void stage_flat(const void* g, void* l, int bytes,
                                           int w, int lane) {
    for (int ofs = w * 1024; ofs < bytes; ofs += 4096)
        gl_lds16((const char*)g + ofs + lane * 16, (char*)l + ofs);
}
// flat async global->LDS copy, 8-wave (512-thr) blocks
__device__ __forceinline__ void stage_flat8(const void* g, void* l, int bytes,
                                            int w, int lane) {
    for (int ofs = w * 1024; ofs < bytes; ofs += 8192)
        gl_lds16((const char*)g + ofs + lane * 16, (char*)l + ofs);
}
__device__ __forceinline__ f32x16 z16() {
    f32x16 v;
#pragma unroll
    for (int i = 0; i < 16; i++) v[i] = 0.f;
    return v;
}
__device__ __forceinline__ bf16x8 cvt8(float4 u, float4 v) {
    return (bf16x8){(__bf16)u.x, (__bf16)u.y, (__bf16)u.z, (__bf16)u.w,
                    (__bf16)v.x, (__bf16)v.y, (__bf16)v.z, (__bf16)v.w};
}
// pack two f32 -> one u32 of 2 bf16 (no builtin on gfx950; m240)
__device__ __forceinline__ unsigned pk2(float lo, float hi) {
    unsigned d;
    asm("v_cvt_pk_bf16_f32 %0, %1, %2" : "=v"(d) : "v"(lo), "v"(hi));
    return d;
}
// swap a.high-lanes <-> b.low-lanes (v_permlane32_swap_b32 modifies both regs)
__device__ __forceinline__ void pl32(unsigned& a, unsigned& b) {
    asm("v_permlane32_swap_b32 %0, %1" : "+v"(a), "+v"(b));
}
__device__ __forceinline__ bf16x8 mk8(unsigned a, unsigned b, unsigned c, unsigned d) {
    union { unsigned u[4]; bf16x8 v; } x;
    x.u[0] = a; x.u[1] = b; x.u[2] = c; x.u[3] = d;
    return x.v;
}

// ---------------------------------------------------------------------------
// Weight conversion.
// z=0/1: WiC/WuC [4 qchunks][160 h][88 kc] (chunk c: k = c*80 + kc, kc<80).
// z=2:   WgT     [2 qchunks][160 h][88 kc].
// z=3:   Wt12    [2][160][168] (unchanged; final_mfma layout).
// ---------------------------------------------------------------------------
__global__ __launch_bounds__(256) void convert_weights(
    const float* __restrict__ Wi, const float* __restrict__ Wu,
    const float* __restrict__ Wg, const float* __restrict__ Wt,
    __bf16* __restrict__ WiC, __bf16* __restrict__ WuC,
    __bf16* __restrict__ WgT, __bf16* __restrict__ Wt12)
{
    const int z = blockIdx.y;
    const int i = blockIdx.x * 256 + threadIdx.x;
    if (z < 2) {
        if (i >= 4 * WCQ) return;
        int c = i / WCQ, rem = i - c * WCQ;
        float v = 0.f;
        if (rem < 160 * KQ) {
            int h = rem / KQ, kc = rem - h * KQ;
            int d = c * 80 + kc;
            if (kc < 80 && d < DD && h < HHH) v = (z ? Wu : Wi)[(size_t)d * HHH + h];
        }
        (z ? WuC : WiC)[i] = (__bf16)v;
    } else if (z == 2) {
        if (i >= 2 * WCQ) return;
        int c = i / WCQ, rem = i - c * WCQ;
        float v = 0.f;
        if (rem < 160 * KQ) {
            int h = rem / KQ, kc = rem - h * KQ;
            int k = c * 80 + kc;
            if (kc < 80 && k < HHH && h < HHH) v = Wg[(size_t)k * HHH + h];
        }
        WgT[i] = (__bf16)v;
    } else {
        if (i >= 2 * 160 * KP) return;
        int c = i / (160 * KP), rem = i - c * (160 * KP);
        int h = rem / KP, kc = rem - h * KP;
        float v = (kc < HHH && h < HHH) ? Wt[(size_t)(c * HHH + kc) * HHH + h] : 0.f;
        Wt12[i] = (__bf16)v;
    }
}

// ---------------------------------------------------------------------------
// gatep v4: occupancy restructure. 64 rows/block, LDS 78.8 KB -> 2 blocks/CU
// (was 148 KB -> 1/CU, fully serial; MfmaUtil 9 / VALU 20 / occ 17%).
// 512 thr / 8 waves: wm = w&1 -> rows wm*32..+31; wn = w>>1 -> h-tiles
// {0,1 | 2 | 3 | 4}. Weights staged in quarter-chunks (80 k) through WB[2]
// double buffer: 8 phases Wi/Wu + 2 phases Wg (z=0). All X frags upfront.
// z=1: Ah = gate(A) -> AhB.  z=0: Qh on-chip -> slab Qg + slab QhT.
// ---------------------------------------------------------------------------
#define GPH(ACC, C, BUF)                                                      \
    for (int ks = 0; ks < 5; ks++) {                                          \
        _Pragma("unroll")                                                     \
        for (int ti = 0; ti < 2; ti++)                                        \
            if (ti < tn)                                                      \
                ACC[ti] = __builtin_amdgcn_mfma_f32_32x32x16_bf16(            \
                    af[C][ks],                                                \
                    *(const bf16x8*)(WB[BUF] + ((tof + ti) * 32 + m32) * KQ + \
                                     ks * 16 + half * 8),                     \
                    ACC[ti], 0, 0, 0);                                        \
    }

__global__ __launch_bounds__(512, 4) void gatep(
    const float* __restrict__ Q, const float* __restrict__ A,
    const __bf16* __restrict__ WiC, const __bf16* __restrict__ WuC,
    const __bf16* __restrict__ WgT,
    const float* __restrict__ bi, const float* __restrict__ bu,
    const float* __restrict__ bg,
    __bf16* __restrict__ AhB, __bf16* __restrict__ Slab)
{
    __shared__ __align__(16) __bf16 WB[2][WCQ];     // 57,344 B
    __shared__ __align__(16) __bf16 QhA[64 * KP];   // 21,504 B
    const int tid = threadIdx.x;
    const int w = tid >> 6, lane = tid & 63;
    const int m32 = lane & 31, half = lane >> 5;
    const int wm = w & 1, wn = w >> 1;
    const int tof = (wn == 0) ? 0 : wn + 1;
    const int tn = (wn == 0) ? 2 : 1;
    const int z = blockIdx.y;
    const int r0 = blockIdx.x * 64;
    const float* X = z ? A : Q;

    stage_flat8(WiC, WB[0], STG_B, w, lane);   // Wi q0; overlaps X loads

    // ---- all X fragments (4 k-chunks x 5 ks), fp32 -> bf16, masked tail ----
    const float* xrow = X + (size_t)(r0 + wm * 32 + m32) * DD;
    bf16x8 af[4][5];
    const float4 zf = {0.f, 0.f, 0.f, 0.f};
#pragma unroll
    for (int c = 0; c < 4; c++)
#pragma unroll
        for (int ks = 0; ks < 5; ks++) {
            const int colb = c * 80 + ks * 16;   // compile-time
            const int col = colb + half * 8;     // runtime (half)
            float4 u = zf, v = zf;
            if (colb + 15 < DD) {
                u = *(const float4*)(xrow + col);
                v = *(const float4*)(xrow + col + 4);
            } else if (colb < DD) {
                if (col + 4 <= DD) u = *(const float4*)(xrow + col);
                if (col + 8 <= DD) v = *(const float4*)(xrow + col + 4);
            }
            af[c][ks] = cvt8(u, v);
        }

    f32x16 ai[2], au[2];
#pragma unroll
    for (int t = 0; t < 2; t++) { ai[t] = z16(); au[t] = z16(); }

    __syncthreads();                                   // WB0 = Wi q0 ready
    stage_flat8(WuC, WB[1], STG_B, w, lane);
    GPH(ai, 0, 0);
    __syncthreads();                                   // WB1 = Wu q0
    stage_flat8(WiC + WCQ, WB[0], STG_B, w, lane);
    GPH(au, 0, 1);
    __syncthreads();                                   // WB0 = Wi q1
    stage_flat8(WuC + WCQ, WB[1], STG_B, w, lane);
    GPH(ai, 1, 0);
    __syncthreads();                                   // WB1 = Wu q1
    stage_flat8(WiC + 2 * WCQ, WB[0], STG_B, w, lane);
    GPH(au, 1, 1);
    __syncthreads();                                   // WB0 = Wi q2
    stage_flat8(WuC + 2 * WCQ, WB[1], STG_B, w, lane);
    GPH(ai, 2, 0);
    __syncthreads();                                   // WB1 = Wu q2
    stage_flat8(WiC + 3 * WCQ, WB[0], STG_B, w, lane);
    GPH(au, 2, 1);
    __syncthreads();                                   // WB0 = Wi q3
    stage_flat8(WuC + 3 * WCQ, WB[1], STG_B, w, lane);
    GPH(ai, 3, 0);
    __syncthreads();                                   // WB1 = Wu q3
    if (z == 0) stage_flat8(WgT, WB[0], STG_B, w, lane);   // prefetch Wg s0
    GPH(au, 3, 1);

    // ---- gate epilogue ----
#pragma unroll
    for (int ti = 0; ti < 2; ti++) {
        if (ti >= tn) continue;
        int h = (tof + ti) * 32 + m32;
        int hc = h < HHH ? h : 0;
        float bih = bi[hc], buh = bu[hc];
#pragma unroll
        for (int r = 0; r < 16; r++) {
            float v = 0.f;
            if (h < HHH) {
                float xi = ai[ti][r] + bih, xu = au[ti][r] + buh;
                float s = 1.f / (1.f + __expf(-xi));
                float tt = 1.f - 2.f / (1.f + __expf(2.f * xu));
                v = s * tt;
            }
            ai[ti][r] = v;
        }
    }

    if (z) {  // A-side: write AhB and exit
#pragma unroll
        for (int ti = 0; ti < 2; ti++) {
            if (ti >= tn) continue;
            int h = (tof + ti) * 32 + m32;
#pragma unroll
            for (int r = 0; r < 16; r++) {
                int rowp = (r & 3) + 8 * (r >> 2) + 4 * half;
                AhB[(size_t)(r0 + wm * 32 + rowp) * KP + h] = (__bf16)ai[ti][r];
            }
        }
        return;
    }

    // ---- Q-side: Qh -> LDS (h cols 0..159, zeros past 149) ----
#pragma unroll
    for (int ti = 0; ti < 2; ti++) {
        if (ti >= tn) continue;
        int h = (tof + ti) * 32 + m32;
#pragma unroll
        for (int r = 0; r < 16; r++) {
            int rowp = (r & 3) + 8 * (r >> 2) + 4 * half;
            QhA[(wm * 32 + rowp) * KP + h] = (__bf16)ai[ti][r];
        }
    }
    __syncthreads();   // QhA visible; Wg s0 in WB0 drained

    stage_flat8(WgT + WCQ, WB[1], STG_B, w, lane);     // Wg s1

    bf16x8 afq[2][5];
#pragma unroll
    for (int s = 0; s < 2; s++)
#pragma unroll
        for (int ks = 0; ks < 5; ks++)
            afq[s][ks] = *(const bf16x8*)(QhA + (wm * 32 + m32) * KP +
                                          s * 80 + ks * 16 + half * 8);

    f32x16 qg[2];
#pragma unroll
    for (int t = 0; t < 2; t++) qg[t] = z16();
    for (int ks = 0; ks < 5; ks++)
#pragma unroll
        for (int ti = 0; ti < 2; ti++)
            if (ti < tn)
                qg[ti] = __builtin_amdgcn_mfma_f32_32x32x16_bf16(
                    afq[0][ks],
                    *(const bf16x8*)(WB[0] + ((tof + ti) * 32 + m32) * KQ + ks * 16 + half * 8),
                    qg[ti], 0, 0, 0);
    __syncthreads();   // WB1 = Wg s1 ready
    for (int ks = 0; ks < 5; ks++)
#pragma unroll
        for (int ti = 0; ti < 2; ti++)
            if (ti < tn)
                qg[ti] = __builtin_amdgcn_mfma_f32_32x32x16_bf16(
                    afq[1][ks],
                    *(const bf16x8*)(WB[1] + ((tof + ti) * 32 + m32) * KQ + ks * 16 + half * 8),
                    qg[ti], 0, 0, 0);

    const int b = r0 >> 11, qt0 = (r0 & 2047) >> 6;
#pragma unroll
    for (int ti = 0; ti < 2; ti++) {
        if (ti >= tn) continue;
        int h = (tof + ti) * 32 + m32;
        int hc = h < HHH ? h : 0;
        float bgh = bg[hc];
#pragma unroll
        for (int r = 0; r < 16; r++) {
            int rowp = (r & 3) + 8 * (r >> 2) + 4 * half;
            int ql = wm * 32 + rowp;
            float v = (h < HHH) ? (qg[ti][r] + bgh) : 0.f;
            Slab[(size_t)(b * 32 + qt0) * SLAB_E + ql * KP + h] = (__bf16)v;
        }
    }

    // QhT transpose-scatter (512 threads, one 64-q tile)
    {
        const int jl = tid & 63, hgrp = tid >> 6;   // 0..7
        __bf16* dst = Slab + (size_t)(b * 32 + qt0) * SLAB_E + QHT_OFF_E + jl;
        for (int hseg = hgrp; hseg < 20; hseg += 8) {
            bf16x8 vv = *(const bf16x8*)(QhA + jl * KP + hseg * 8);
#pragma unroll
            for (int e = 0; e < 8; e++)
                dst[(hseg * 8 + e) * QTS] = vv[e];
        }
    }
}

// ---------------------------------------------------------------------------
// attn v9 (unchanged from R2): T12 in-register P + 3-deep counted-vmcnt
// pipeline (vmcnt(5) steady state, never 0 until drain).
// ---------------------------------------------------------------------------
__global__ __launch_bounds__(512, 2) void attn_mfma(
    const __bf16* __restrict__ Slab, const __bf16* __restrict__ AhB,
    __bf16* __restrict__ O, float* __restrict__ L)
{
    __shared__ __align__(16) __bf16 Buf[3][SLAB_E];   // 138,240 B
    const int tid = threadIdx.x;
    const int w = tid >> 6, lane = tid & 63;
    const int m32 = lane & 31, half = lane >> 5;
    const int grp = blockIdx.x;            // 0..31 = b*4 + qp
    const int b = grp >> 2, qp = grp & 3;
    const int a0 = blockIdx.y * 256;

    const char* slabBase = (const char*)Slab + (size_t)(b * 32 + qp * 8) * SLAB_B;
    stage_flat8(slabBase, Buf[0], SLAB_B, w, lane);           // t0: 5-6 loads
    __builtin_amdgcn_sched_barrier(0);

    // A-fragments from global (pinned between the two stage batches so the
    // prologue vmcnt(15) counts exactly: t0(<=6) + af(10) + t1(<=6))
    const __bf16* arow = AhB + (size_t)(b * LQ + a0 + w * 32 + m32) * KP + half * 8;
    bf16x8 af[10];
#pragma unroll
    for (int ks = 0; ks < 10; ks++)
        af[ks] = *(const bf16x8*)(arow + ks * 16);
    __builtin_amdgcn_sched_barrier(0);

    stage_flat8(slabBase + SLAB_B, Buf[1], SLAB_B, w, lane);  // t1
    __builtin_amdgcn_sched_barrier(0);
    asm volatile("s_waitcnt vmcnt(15)" ::: "memory");          // t0 landed
    __builtin_amdgcn_sched_barrier(0);
    __builtin_amdgcn_s_barrier();
    __builtin_amdgcn_sched_barrier(0);

    float lsum = 0.f;
    f32x16 acc[5];
#pragma unroll
    for (int t = 0; t < 5; t++) acc[t] = z16();

    for (int qt = 0; qt < 8; qt++) {
        if (qt < 6)
            stage_flat8(slabBase + (size_t)(qt + 2) * SLAB_B, Buf[(qt + 2) % 3],
                        SLAB_B, w, lane);
        const __bf16* Bq = Buf[qt % 3];
        const __bf16* Bv = Bq + QHT_OFF_E;

        // S^T = Qg(64q rows) x Ah(32a cols), K=160 -> two 32x32 tiles
        f32x16 s0 = z16(), s1 = z16();
        __builtin_amdgcn_s_setprio(1);
        for (int ks = 0; ks < 10; ks++) {
            bf16x8 b0 = *(const bf16x8*)(Bq + m32 * KP + ks * 16 + half * 8);
            bf16x8 b1 = *(const bf16x8*)(Bq + (32 + m32) * KP + ks * 16 + half * 8);
            s0 = __builtin_amdgcn_mfma_f32_32x32x16_bf16(b0, af[ks], s0, 0, 0, 0);
            s1 = __builtin_amdgcn_mfma_f32_32x32x16_bf16(b1, af[ks], s1, 0, 0, 0);
        }
        __builtin_amdgcn_s_setprio(0);

        // P = exp(S) in-register; accumulate l (lane's column a = m32)
#pragma unroll
        for (int r = 0; r < 16; r++) { s0[r] = __expf(s0[r]); lsum += s0[r]; }
#pragma unroll
        for (int r = 0; r < 16; r++) { s1[r] = __expf(s1[r]); lsum += s1[r]; }

        // Build PV B-frags in-register (T12): cvt_pk + permlane32_swap.
        bf16x8 pf[4];
        {
            unsigned w01 = pk2(s0[0], s0[1]),   w45 = pk2(s0[4], s0[5]);
            unsigned w23 = pk2(s0[2], s0[3]),   w67 = pk2(s0[6], s0[7]);
            pl32(w01, w45); pl32(w23, w67);
            pf[0] = mk8(w01, w23, w45, w67);
            unsigned x01 = pk2(s0[8], s0[9]),   x45 = pk2(s0[12], s0[13]);
            unsigned x23 = pk2(s0[10], s0[11]), x67 = pk2(s0[14], s0[15]);
            pl32(x01, x45); pl32(x23, x67);
            pf[1] = mk8(x01, x23, x45, x67);
        }
        {
            unsigned w01 = pk2(s1[0], s1[1]),   w45 = pk2(s1[4], s1[5]);
            unsigned w23 = pk2(s1[2], s1[3]),   w67 = pk2(s1[6], s1[7]);
            pl32(w01, w45); pl32(w23, w67);
            pf[2] = mk8(w01, w23, w45, w67);
            unsigned x01 = pk2(s1[8], s1[9]),   x45 = pk2(s1[12], s1[13]);
            unsigned x23 = pk2(s1[10], s1[11]), x67 = pk2(s1[14], s1[15]);
            pl32(x01, x45); pl32(x23, x67);
            pf[3] = mk8(x01, x23, x45, x67);
        }

        // O^T: acc[t] = QhT(h-rows) x P(a-cols) -> O[a=m32][h = t*32 + rowp]
        __builtin_amdgcn_s_setprio(1);
#pragma unroll
        for (int kk = 0; kk < 4; kk++)
#pragma unroll
            for (int t = 0; t < 5; t++)
                acc[t] = __builtin_amdgcn_mfma_f32_32x32x16_bf16(
                    *(const bf16x8*)(Bv + (t * 32 + m32) * QTS + kk * 16 + half * 8),
                    pf[kk], acc[t], 0, 0, 0);
        __builtin_amdgcn_s_setprio(0);

        if (qt < 7) {
            __builtin_amdgcn_sched_barrier(0);
            if (qt < 6) asm volatile("s_waitcnt vmcnt(5)" ::: "memory");
            else        asm volatile("s_waitcnt vmcnt(0)" ::: "memory");
            __builtin_amdgcn_sched_barrier(0);
            __builtin_amdgcn_s_barrier();
            __builtin_amdgcn_sched_barrier(0);
        }
    }

    // l: this lane has half the q's of column a=m32; partner lane^32 the rest
    float lt = lsum + __shfl_xor(lsum, 32, 64);

    // O store: row a = w*32 + m32; h = t*32 + rq*8 + half*4 + j (contiguous 4)
    __bf16* Ob = O + ((size_t)qp * NROWS + b * LQ + a0 + w * 32) * 160;
#pragma unroll
    for (int t = 0; t < 5; t++)
#pragma unroll
        for (int rq = 0; rq < 4; rq++) {
            bf16x4 hv = {(__bf16)acc[t][rq * 4 + 0], (__bf16)acc[t][rq * 4 + 1],
                         (__bf16)acc[t][rq * 4 + 2], (__bf16)acc[t][rq * 4 + 3]};
            *(bf16x4*)(Ob + (size_t)m32 * 160 + t * 32 + rq * 8 + half * 4) = hv;
        }
    if (half == 0)
        L[(size_t)qp * NROWS + b * LQ + a0 + w * 32 + m32] = lt;
}

// ---------------------------------------------------------------------------
// final (unchanged): Hm = (sum of 4 O partials)/(sum l);
// Out = relu([Ah,Hm]@Wt+bt). Wt staged in LDS (WtS).
// ---------------------------------------------------------------------------
__global__ __launch_bounds__(256, 1) void final_mfma(
    const __bf16* __restrict__ AhB, const __bf16* __restrict__ O,
    const float* __restrict__ L, const __bf16* __restrict__ Wt12,
    const float* __restrict__ bt, float* __restrict__ Out)
{
    __shared__ __align__(16) __bf16 AS[64 * KP];          // 21504 B
    __shared__ __align__(16) __bf16 HS[64 * KP];          // 21504 B
    __shared__ __align__(16) __bf16 WtS[2 * 160 * KP];    // 107520 B
    const int tid = threadIdx.x;
    const int w = tid >> 6, lane = tid & 63;
    const int m32 = lane & 31, half = lane >> 5;
    const int r0 = blockIdx.x * 64;

    stage_flat(AhB + (size_t)r0 * KP, AS, 21504, w, lane);
    stage_flat(Wt12, WtS, 107520, w, lane);

    // combine 4 partials -> HS
    {
        int rhat = tid >> 2, qq = tid & 3;
        int grow = r0 + rhat;
        float inv = 1.f / (L[grow] + L[NROWS + grow] + L[2 * NROWS + grow] + L[3 * NROWS + grow]);
#pragma unroll
        for (int k = 0; k < 5; k++) {
            float sum[8];
#pragma unroll
            for (int j = 0; j < 8; j++) sum[j] = 0.f;
#pragma unroll
            for (int p = 0; p < 4; p++) {
                bf16x8 x = *(const bf16x8*)(O + ((size_t)p * NROWS + grow) * 160 + qq * 40 + k * 8);
#pragma unroll
                for (int j = 0; j < 8; j++) sum[j] += (float)x[j];
            }
            bf16x8 hv;
#pragma unroll
            for (int j = 0; j < 8; j++) hv[j] = (__bf16)(sum[j] * inv);
            *(bf16x8*)(HS + rhat * KP + qq * 40 + k * 8) = hv;
        }
    }
    __syncthreads();

    const int m = w & 1, th = w >> 1;
    const int tbase = th ? 3 : 0, tn = th ? 2 : 3;
    f32x16 acc[3];
#pragma unroll
    for (int i = 0; i < 3; i++) acc[i] = z16();

    for (int ch = 0; ch < 2; ch++) {
        const __bf16* src = ch ? HS : AS;
        for (int ks = 0; ks < 10; ks++) {
            bf16x8 af = *(const bf16x8*)(src + (m * 32 + m32) * KP + ks * 16 + half * 8);
#pragma unroll
            for (int ti = 0; ti < 3; ti++) {
                if (ti < tn) {
                    int t = tbase + ti;
                    acc[ti] = __builtin_amdgcn_mfma_f32_32x32x16_bf16(
                        af, *(const bf16x8*)(WtS + (ch * 160 + t * 32 + m32) * KP + ks * 16 + half * 8),
                        acc[ti], 0, 0, 0);
                }
            }
        }
    }

#pragma unroll
    for (int ti = 0; ti < 3; ti++) {
        if (ti < tn) {
            int t = tbase + ti;
            int h = t * 32 + m32;
            if (h < HHH) {
                float bth = bt[h];
#pragma unroll
                for (int r = 0; r < 16; r++) {
                    int rowp = (r & 3) + 8 * (r >> 2) + 4 * half;
                    float v = acc[ti][r] + bth;
                    Out[(size_t)(r0 + m * 32 + rowp) * HHH + h] = v > 0.f ? v : 0.f;
                }
            }
        }
    }
}

// ---------------------------------------------------------------------------
extern "C" void kernel_launch(void* const* d_in, const int* in_sizes, int n_in,
                              void* d_out, int out_size, void* d_ws, size_t ws_size,
                              hipStream_t stream)
{
    const float* Q  = (const float*)d_in[0];
    const float* A  = (const float*)d_in[1];
    const float* Wi = (const float*)d_in[2];
    const float* Wu = (const float*)d_in[3];
    const float* Wg = (const float*)d_in[4];
    const float* Wt = (const float*)d_in[5];
    const float* bi = (const float*)d_in[6];
    const float* bu = (const float*)d_in[7];
    const float* bg = (const float*)d_in[8];
    const float* bt = (const float*)d_in[9];
    float* out = (float*)d_out;

    char* ws = (char*)d_ws;
    __bf16* Slab = (__bf16*)(ws);                    // 11,796,480 B (256 x 46,080)
    __bf16* AhB  = (__bf16*)(ws + 11796480);         //  5,505,024 B
    __bf16* Op   = (__bf16*)(ws + 17301504);         // 20,971,520 B (4 partials)
    float*  Lp   = (float*) (ws + 38273024);         //    262,144 B (4 partials)
    __bf16* WiC  = (__bf16*)(ws + 38535168);         //    114,688 B (4 x 14336 x 2)
    __bf16* WuC  = (__bf16*)(ws + 38649856);         //    114,688 B
    __bf16* WgT  = (__bf16*)(ws + 38764544);         //     57,344 B (2 x 14336 x 2)
    __bf16* Wt12 = (__bf16*)(ws + 38821888);         //    107,520 B

    convert_weights<<<dim3(224, 4), 256, 0, stream>>>(Wi, Wu, Wg, Wt,
                                                      WiC, WuC, WgT, Wt12);
    gatep<<<dim3(NROWS / 64, 2), 512, 0, stream>>>(Q, A, WiC, WuC, WgT,
                                                   bi, bu, bg, AhB, Slab);
    attn_mfma<<<dim3(32, 8), 512, 0, stream>>>(Slab, AhB, Op, Lp);
    final_mfma<<<NROWS / 64, 256, 0, stream>>>(AhB, Op, Lp, Wt12, bt, out);
}

// Round 5
// 162.550 us; speedup vs baseline: 1.7268x; 1.2888x over previous
//
#include <hip/hip_runtime.h>
#include <math.h>

#define BB 8
#define LQ 2048
#define DD 300
#define HHH 150
#define NROWS (BB * LQ)

#define KP 168          // row stride (elems) for AhB / Qg / QhA / Wt rows (336 B)
#define QTS 72          // QhT q-stride (144 B)
#define KQ 88           // W chunk row stride (elems, 176 B, 16B-aligned)
#define WCQ 16384       // elems per W chunk buffer (32 KB; uniform 4 loads/wave)
#define STG_B 32768     // staged bytes per chunk
#define SLAB_B 46080    // per-(b,qt) slab bytes (45 KiB)
#define SLAB_E 23040    // slab elems; used: Qg 64x168 | QhT @11008 160x72
#define QHT_OFF_E 11008

typedef __bf16 bf16x8 __attribute__((ext_vector_type(8)));
typedef __bf16 bf16x4 __attribute__((ext_vector_type(4)));
typedef float f32x16 __attribute__((ext_vector_type(16)));

__device__ __forceinline__ void gl_lds16(const void* g, void* l) {
    __builtin_amdgcn_global_load_lds(
        (const __attribute__((address_space(1))) void*)g,
        (__attribute__((address_space(3))) void*)l,
        16, 0, 0);
}
// flat async global->LDS copy, 4-wave (256-thr) blocks
__device__ __forceinline__ void stage_flat(const void* g, void* l, int bytes,
                                           int w, int lane) {
    for (int ofs = w * 1024; ofs < bytes; ofs += 4096)
        gl_lds16((const char*)g + ofs + lane * 16, (char*)l + ofs);
}
// flat async global->LDS copy, 8-wave (512-thr) blocks
__device__ __forceinline__ void stage_flat8(const void* g, void* l, int bytes,
                                            int w, int lane) {
    for (int ofs = w * 1024; ofs < bytes; ofs += 8192)
        gl_lds16((const char*)g + ofs + lane * 16, (char*)l + ofs);
}
__device__ __forceinline__ f32x16 z16() {
    f32x16 v;
#pragma unroll
    for (int i = 0; i < 16; i++) v[i] = 0.f;
    return v;
}
__device__ __forceinline__ bf16x8 cvt8(float4 u, float4 v) {
    return (bf16x8){(__bf16)u.x, (__bf16)u.y, (__bf16)u.z, (__bf16)u.w,
                    (__bf16)v.x, (__bf16)v.y, (__bf16)v.z, (__bf16)v.w};
}
// pack two f32 -> one u32 of 2 bf16 (no builtin on gfx950; m240)
__device__ __forceinline__ unsigned pk2(float lo, float hi) {
    unsigned d;
    asm("v_cvt_pk_bf16_f32 %0, %1, %2" : "=v"(d) : "v"(lo), "v"(hi));
    return d;
}
// swap a.high-lanes <-> b.low-lanes (v_permlane32_swap_b32 modifies both regs)
__device__ __forceinline__ void pl32(unsigned& a, unsigned& b) {
    asm("v_permlane32_swap_b32 %0, %1" : "+v"(a), "+v"(b));
}
__device__ __forceinline__ bf16x8 mk8(unsigned a, unsigned b, unsigned c, unsigned d) {
    union { unsigned u[4]; bf16x8 v; } x;
    x.u[0] = a; x.u[1] = b; x.u[2] = c; x.u[3] = d;
    return x.v;
}

// ---------------------------------------------------------------------------
// Weight conversion.
// z=0/1: WiC/WuC [4 chunks][16384] (row h*88 + kc; chunk c: k = c*80 + kc).
// z=2:   WgT     [2 chunks][16384].
// z=3:   Wt12    [2][160][168] (final_mfma layout, unchanged).
// ---------------------------------------------------------------------------
__global__ __launch_bounds__(256) void convert_weights(
    const float* __restrict__ Wi, const float* __restrict__ Wu,
    const float* __restrict__ Wg, const float* __restrict__ Wt,
    __bf16* __restrict__ WiC, __bf16* __restrict__ WuC,
    __bf16* __restrict__ WgT, __bf16* __restrict__ Wt12)
{
    const int z = blockIdx.y;
    const int i = blockIdx.x * 256 + threadIdx.x;
    if (z < 2) {
        if (i >= 4 * WCQ) return;
        int c = i >> 14, rem = i & (WCQ - 1);
        float v = 0.f;
        if (rem < 160 * KQ) {
            int h = rem / KQ, kc = rem - h * KQ;
            int d = c * 80 + kc;
            if (kc < 80 && d < DD && h < HHH) v = (z ? Wu : Wi)[(size_t)d * HHH + h];
        }
        (z ? WuC : WiC)[i] = (__bf16)v;
    } else if (z == 2) {
        if (i >= 2 * WCQ) return;
        int c = i >> 14, rem = i & (WCQ - 1);
        float v = 0.f;
        if (rem < 160 * KQ) {
            int h = rem / KQ, kc = rem - h * KQ;
            int k = c * 80 + kc;
            if (kc < 80 && k < HHH && h < HHH) v = Wg[(size_t)k * HHH + h];
        }
        WgT[i] = (__bf16)v;
    } else {
        if (i >= 2 * 160 * KP) return;
        int c = i / (160 * KP), rem = i - c * (160 * KP);
        int h = rem / KP, kc = rem - h * KP;
        float v = (kc < HHH && h < HHH) ? Wt[(size_t)(c * HHH + kc) * HHH + h] : 0.f;
        Wt12[i] = (__bf16)v;
    }
}

// ---------------------------------------------------------------------------
// gatep v5: v3 geometry (128 rows/block, 256 blocks) + T3/T4 pipelined weight
// staging. Chunks p=0..9: even=Wi q(p/2), odd=Wu q(p/2), 8/9=Wg s0/s1.
// WB[3] rotation: top of phase p stages chunk p+2 into slot (p+2)%3; tail is
// sched_barrier + s_waitcnt vmcnt(4) (chunk p+1 landed, p+2 stays in flight)
// + raw s_barrier. Never vmcnt(0) mid-pipeline. Uniform 4 loads/wave/chunk.
// 8 waves: wm=w&3 rows wm*32..+31; wn=w>>2 h-tiles {0,1,2 | 3,4}.
// z=1: Ah=gate(A)->AhB (8 phases). z=0: +Wg phases -> slab Qg + slab QhT.
// ---------------------------------------------------------------------------
__global__ __launch_bounds__(512, 2) void gatep(
    const float* __restrict__ Q, const float* __restrict__ A,
    const __bf16* __restrict__ WiC, const __bf16* __restrict__ WuC,
    const __bf16* __restrict__ WgT,
    const float* __restrict__ bi, const float* __restrict__ bu,
    const float* __restrict__ bg,
    __bf16* __restrict__ AhB, __bf16* __restrict__ Slab)
{
    __shared__ __align__(16) __bf16 WB[3][WCQ];      // 98,304 B
    __shared__ __align__(16) __bf16 QhA[128 * KP];   // 43,008 B
    const int tid = threadIdx.x;
    const int w = tid >> 6, lane = tid & 63;
    const int m32 = lane & 31, half = lane >> 5;
    const int wm = w & 3, wn = w >> 2;
    const int tof = wn ? 3 : 0, tn = wn ? 2 : 3;
    const int z = blockIdx.y;
    const int r0 = blockIdx.x * 128;
    const float* X = z ? A : Q;
    const int lim = z ? 8 : 10;     // chunks staged (z=1 skips Wg)

#define STGP(P)                                                               \
    do {                                                                      \
        const __bf16* _src = ((P) < 8)                                        \
            ? (((P) & 1) ? WuC + ((P) >> 1) * WCQ : WiC + ((P) >> 1) * WCQ)   \
            : WgT + ((P) - 8) * WCQ;                                          \
        stage_flat8(_src, WB[(P) % 3], STG_B, w, lane);                       \
    } while (0)

    STGP(0);
    STGP(1);
    __builtin_amdgcn_sched_barrier(0);

    // ---- all X fragments (4 k-chunks x 5 ks), fp32 -> bf16, masked tail ----
    // Issued AFTER chunk 0/1 stages; the cvt drains force (in-order vmcnt)
    // chunks 0/1 retired as well by the prologue barrier.
    const float* xrow = X + (size_t)(r0 + wm * 32 + m32) * DD;
    bf16x8 af[4][5];
    const float4 zf = {0.f, 0.f, 0.f, 0.f};
#pragma unroll
    for (int c = 0; c < 4; c++)
#pragma unroll
        for (int ks = 0; ks < 5; ks++) {
            const int colb = c * 80 + ks * 16;   // compile-time
            const int col = colb + half * 8;     // runtime (half)
            float4 u = zf, v = zf;
            if (colb + 15 < DD) {
                u = *(const float4*)(xrow + col);
                v = *(const float4*)(xrow + col + 4);
            } else if (colb < DD) {
                if (col + 4 <= DD) u = *(const float4*)(xrow + col);
                if (col + 8 <= DD) v = *(const float4*)(xrow + col + 4);
            }
            af[c][ks] = cvt8(u, v);
        }

    f32x16 ai[3], au[3];
#pragma unroll
    for (int t = 0; t < 3; t++) { ai[t] = z16(); au[t] = z16(); }

    __builtin_amdgcn_sched_barrier(0);
    asm volatile("s_waitcnt vmcnt(0)" ::: "memory");   // prologue: c0+c1 landed
    __builtin_amdgcn_s_barrier();
    __builtin_amdgcn_sched_barrier(0);

#define GPHASE(P, ACC, C)                                                     \
    {                                                                         \
        if ((P) + 2 < lim) { STGP((P) + 2); }                                 \
        const __bf16* Wb = WB[(P) % 3];                                       \
        _Pragma("unroll")                                                     \
        for (int ks = 0; ks < 5; ks++) {                                      \
            _Pragma("unroll")                                                 \
            for (int ti = 0; ti < 3; ti++)                                    \
                if (ti < tn)                                                  \
                    ACC[ti] = __builtin_amdgcn_mfma_f32_32x32x16_bf16(        \
                        af[C][ks],                                            \
                        *(const bf16x8*)(Wb + ((tof + ti) * 32 + m32) * KQ +  \
                                         ks * 16 + half * 8),                 \
                        ACC[ti], 0, 0, 0);                                    \
        }                                                                     \
        __builtin_amdgcn_sched_barrier(0);                                    \
        if ((P) + 2 < lim)                                                    \
            asm volatile("s_waitcnt vmcnt(4)" ::: "memory");                  \
        else                                                                  \
            asm volatile("s_waitcnt vmcnt(0)" ::: "memory");                  \
        __builtin_amdgcn_sched_barrier(0);                                    \
        __builtin_amdgcn_s_barrier();                                         \
        __builtin_amdgcn_sched_barrier(0);                                    \
    }

    GPHASE(0, ai, 0)
    GPHASE(1, au, 0)
    GPHASE(2, ai, 1)
    GPHASE(3, au, 1)
    GPHASE(4, ai, 2)
    GPHASE(5, au, 2)
    GPHASE(6, ai, 3)
    GPHASE(7, au, 3)

    // ---- gate epilogue ----
#pragma unroll
    for (int ti = 0; ti < 3; ti++) {
        if (ti >= tn) continue;
        int h = (tof + ti) * 32 + m32;
        int hc = h < HHH ? h : 0;
        float bih = bi[hc], buh = bu[hc];
#pragma unroll
        for (int r = 0; r < 16; r++) {
            float v = 0.f;
            if (h < HHH) {
                float xi = ai[ti][r] + bih, xu = au[ti][r] + buh;
                float s = 1.f / (1.f + __expf(-xi));
                float tt = 1.f - 2.f / (1.f + __expf(2.f * xu));
                v = s * tt;
            }
            ai[ti][r] = v;
        }
    }

    if (z) {  // A-side: write AhB and exit
#pragma unroll
        for (int ti = 0; ti < 3; ti++) {
            if (ti >= tn) continue;
            int h = (tof + ti) * 32 + m32;
#pragma unroll
            for (int r = 0; r < 16; r++) {
                int rowp = (r & 3) + 8 * (r >> 2) + 4 * half;
                AhB[(size_t)(r0 + wm * 32 + rowp) * KP + h] = (__bf16)ai[ti][r];
            }
        }
        return;
    }

    // ---- Q-side: Qh -> LDS (rows shared across wn halves) ----
#pragma unroll
    for (int ti = 0; ti < 3; ti++) {
        if (ti >= tn) continue;
        int h = (tof + ti) * 32 + m32;
#pragma unroll
        for (int r = 0; r < 16; r++) {
            int rowp = (r & 3) + 8 * (r >> 2) + 4 * half;
            QhA[(wm * 32 + rowp) * KP + h] = (__bf16)ai[ti][r];
        }
    }
    __syncthreads();   // QhA visible; Wg s0 (chunk 8, WB[2]) landed at P7 tail

    bf16x8 afq[2][5];
#pragma unroll
    for (int s = 0; s < 2; s++)
#pragma unroll
        for (int ks = 0; ks < 5; ks++)
            afq[s][ks] = *(const bf16x8*)(QhA + (wm * 32 + m32) * KP +
                                          s * 80 + ks * 16 + half * 8);

    f32x16 qg[3];
#pragma unroll
    for (int t = 0; t < 3; t++) qg[t] = z16();
#pragma unroll
    for (int ks = 0; ks < 5; ks++)
#pragma unroll
        for (int ti = 0; ti < 3; ti++)
            if (ti < tn)
                qg[ti] = __builtin_amdgcn_mfma_f32_32x32x16_bf16(
                    afq[0][ks],
                    *(const bf16x8*)(WB[2] + ((tof + ti) * 32 + m32) * KQ + ks * 16 + half * 8),
                    qg[ti], 0, 0, 0);
    __builtin_amdgcn_sched_barrier(0);
    asm volatile("s_waitcnt vmcnt(0)" ::: "memory");   // Wg s1 (chunk 9, WB[0])
    __builtin_amdgcn_s_barrier();
    __builtin_amdgcn_sched_barrier(0);
#pragma unroll
    for (int ks = 0; ks < 5; ks++)
#pragma unroll
        for (int ti = 0; ti < 3; ti++)
            if (ti < tn)
                qg[ti] = __builtin_amdgcn_mfma_f32_32x32x16_bf16(
                    afq[1][ks],
                    *(const bf16x8*)(WB[0] + ((tof + ti) * 32 + m32) * KQ + ks * 16 + half * 8),
                    qg[ti], 0, 0, 0);

    const int b = r0 >> 11, qt0 = (r0 & 2047) >> 6;
#pragma unroll
    for (int ti = 0; ti < 3; ti++) {
        if (ti >= tn) continue;
        int h = (tof + ti) * 32 + m32;
        int hc = h < HHH ? h : 0;
        float bgh = bg[hc];
#pragma unroll
        for (int r = 0; r < 16; r++) {
            int rowp = (r & 3) + 8 * (r >> 2) + 4 * half;
            int q = (r0 & 2047) + wm * 32 + rowp;
            float v = (h < HHH) ? (qg[ti][r] + bgh) : 0.f;
            Slab[(size_t)(b * 32 + (q >> 6)) * SLAB_E + (q & 63) * KP + h] = (__bf16)v;
        }
    }

    // QhT transpose-scatter (512 threads, two 64-q tiles)
    {
        const int jl = tid & 63, tile = (tid >> 6) & 1, hgrp = tid >> 7;
        for (int hseg = hgrp; hseg < 20; hseg += 4) {
            bf16x8 vv = *(const bf16x8*)(QhA + (tile * 64 + jl) * KP + hseg * 8);
            __bf16* dst = Slab + (size_t)(b * 32 + qt0 + tile) * SLAB_E + QHT_OFF_E + jl;
#pragma unroll
            for (int e = 0; e < 8; e++)
                dst[(hseg * 8 + e) * QTS] = vv[e];
        }
    }
}

// ---------------------------------------------------------------------------
// attn v9 (unchanged): T12 in-register P + 3-deep counted-vmcnt pipeline.
// ---------------------------------------------------------------------------
__global__ __launch_bounds__(512, 2) void attn_mfma(
    const __bf16* __restrict__ Slab, const __bf16* __restrict__ AhB,
    __bf16* __restrict__ O, float* __restrict__ L)
{
    __shared__ __align__(16) __bf16 Buf[3][SLAB_E];   // 138,240 B
    const int tid = threadIdx.x;
    const int w = tid >> 6, lane = tid & 63;
    const int m32 = lane & 31, half = lane >> 5;
    const int grp = blockIdx.x;            // 0..31 = b*4 + qp
    const int b = grp >> 2, qp = grp & 3;
    const int a0 = blockIdx.y * 256;

    const char* slabBase = (const char*)Slab + (size_t)(b * 32 + qp * 8) * SLAB_B;
    stage_flat8(slabBase, Buf[0], SLAB_B, w, lane);           // t0: 5-6 loads
    __builtin_amdgcn_sched_barrier(0);

    const __bf16* arow = AhB + (size_t)(b * LQ + a0 + w * 32 + m32) * KP + half * 8;
    bf16x8 af[10];
#pragma unroll
    for (int ks = 0; ks < 10; ks++)
        af[ks] = *(const bf16x8*)(arow + ks * 16);
    __builtin_amdgcn_sched_barrier(0);

    stage_flat8(slabBase + SLAB_B, Buf[1], SLAB_B, w, lane);  // t1
    __builtin_amdgcn_sched_barrier(0);
    asm volatile("s_waitcnt vmcnt(15)" ::: "memory");          // t0 landed
    __builtin_amdgcn_sched_barrier(0);
    __builtin_amdgcn_s_barrier();
    __builtin_amdgcn_sched_barrier(0);

    float lsum = 0.f;
    f32x16 acc[5];
#pragma unroll
    for (int t = 0; t < 5; t++) acc[t] = z16();

    for (int qt = 0; qt < 8; qt++) {
        if (qt < 6)
            stage_flat8(slabBase + (size_t)(qt + 2) * SLAB_B, Buf[(qt + 2) % 3],
                        SLAB_B, w, lane);
        const __bf16* Bq = Buf[qt % 3];
        const __bf16* Bv = Bq + QHT_OFF_E;

        // S^T = Qg(64q rows) x Ah(32a cols), K=160 -> two 32x32 tiles
        f32x16 s0 = z16(), s1 = z16();
        __builtin_amdgcn_s_setprio(1);
        for (int ks = 0; ks < 10; ks++) {
            bf16x8 b0 = *(const bf16x8*)(Bq + m32 * KP + ks * 16 + half * 8);
            bf16x8 b1 = *(const bf16x8*)(Bq + (32 + m32) * KP + ks * 16 + half * 8);
            s0 = __builtin_amdgcn_mfma_f32_32x32x16_bf16(b0, af[ks], s0, 0, 0, 0);
            s1 = __builtin_amdgcn_mfma_f32_32x32x16_bf16(b1, af[ks], s1, 0, 0, 0);
        }
        __builtin_amdgcn_s_setprio(0);

        // P = exp(S) in-register; accumulate l (lane's column a = m32)
#pragma unroll
        for (int r = 0; r < 16; r++) { s0[r] = __expf(s0[r]); lsum += s0[r]; }
#pragma unroll
        for (int r = 0; r < 16; r++) { s1[r] = __expf(s1[r]); lsum += s1[r]; }

        // Build PV B-frags in-register (T12): cvt_pk + permlane32_swap.
        bf16x8 pf[4];
        {
            unsigned w01 = pk2(s0[0], s0[1]),   w45 = pk2(s0[4], s0[5]);
            unsigned w23 = pk2(s0[2], s0[3]),   w67 = pk2(s0[6], s0[7]);
            pl32(w01, w45); pl32(w23, w67);
            pf[0] = mk8(w01, w23, w45, w67);
            unsigned x01 = pk2(s0[8], s0[9]),   x45 = pk2(s0[12], s0[13]);
            unsigned x23 = pk2(s0[10], s0[11]), x67 = pk2(s0[14], s0[15]);
            pl32(x01, x45); pl32(x23, x67);
            pf[1] = mk8(x01, x23, x45, x67);
        }
        {
            unsigned w01 = pk2(s1[0], s1[1]),   w45 = pk2(s1[4], s1[5]);
            unsigned w23 = pk2(s1[2], s1[3]),   w67 = pk2(s1[6], s1[7]);
            pl32(w01, w45); pl32(w23, w67);
            pf[2] = mk8(w01, w23, w45, w67);
            unsigned x01 = pk2(s1[8], s1[9]),   x45 = pk2(s1[12], s1[13]);
            unsigned x23 = pk2(s1[10], s1[11]), x67 = pk2(s1[14], s1[15]);
            pl32(x01, x45); pl32(x23, x67);
            pf[3] = mk8(x01, x23, x45, x67);
        }

        // O^T: acc[t] = QhT(h-rows) x P(a-cols) -> O[a=m32][h = t*32 + rowp]
        __builtin_amdgcn_s_setprio(1);
#pragma unroll
        for (int kk = 0; kk < 4; kk++)
#pragma unroll
            for (int t = 0; t < 5; t++)
                acc[t] = __builtin_amdgcn_mfma_f32_32x32x16_bf16(
                    *(const bf16x8*)(Bv + (t * 32 + m32) * QTS + kk * 16 + half * 8),
                    pf[kk], acc[t], 0, 0, 0);
        __builtin_amdgcn_s_setprio(0);

        if (qt < 7) {
            __builtin_amdgcn_sched_barrier(0);
            if (qt < 6) asm volatile("s_waitcnt vmcnt(5)" ::: "memory");
            else        asm volatile("s_waitcnt vmcnt(0)" ::: "memory");
            __builtin_amdgcn_sched_barrier(0);
            __builtin_amdgcn_s_barrier();
            __builtin_amdgcn_sched_barrier(0);
        }
    }

    // l: this lane has half the q's of column a=m32; partner lane^32 the rest
    float lt = lsum + __shfl_xor(lsum, 32, 64);

    // O store: row a = w*32 + m32; h = t*32 + rq*8 + half*4 + j (contiguous 4)
    __bf16* Ob = O + ((size_t)qp * NROWS + b * LQ + a0 + w * 32) * 160;
#pragma unroll
    for (int t = 0; t < 5; t++)
#pragma unroll
        for (int rq = 0; rq < 4; rq++) {
            bf16x4 hv = {(__bf16)acc[t][rq * 4 + 0], (__bf16)acc[t][rq * 4 + 1],
                         (__bf16)acc[t][rq * 4 + 2], (__bf16)acc[t][rq * 4 + 3]};
            *(bf16x4*)(Ob + (size_t)m32 * 160 + t * 32 + rq * 8 + half * 4) = hv;
        }
    if (half == 0)
        L[(size_t)qp * NROWS + b * LQ + a0 + w * 32 + m32] = lt;
}

// ---------------------------------------------------------------------------
// final (unchanged): Hm = (sum of 4 O partials)/(sum l);
// Out = relu([Ah,Hm]@Wt+bt). Wt staged in LDS (WtS).
// ---------------------------------------------------------------------------
__global__ __launch_bounds__(256, 1) void final_mfma(
    const __bf16* __restrict__ AhB, const __bf16* __restrict__ O,
    const float* __restrict__ L, const __bf16* __restrict__ Wt12,
    const float* __restrict__ bt, float* __restrict__ Out)
{
    __shared__ __align__(16) __bf16 AS[64 * KP];          // 21504 B
    __shared__ __align__(16) __bf16 HS[64 * KP];          // 21504 B
    __shared__ __align__(16) __bf16 WtS[2 * 160 * KP];    // 107520 B
    const int tid = threadIdx.x;
    const int w = tid >> 6, lane = tid & 63;
    const int m32 = lane & 31, half = lane >> 5;
    const int r0 = blockIdx.x * 64;

    stage_flat(AhB + (size_t)r0 * KP, AS, 21504, w, lane);
    stage_flat(Wt12, WtS, 107520, w, lane);

    // combine 4 partials -> HS
    {
        int rhat = tid >> 2, qq = tid & 3;
        int grow = r0 + rhat;
        float inv = 1.f / (L[grow] + L[NROWS + grow] + L[2 * NROWS + grow] + L[3 * NROWS + grow]);
#pragma unroll
        for (int k = 0; k < 5; k++) {
            float sum[8];
#pragma unroll
            for (int j = 0; j < 8; j++) sum[j] = 0.f;
#pragma unroll
            for (int p = 0; p < 4; p++) {
                bf16x8 x = *(const bf16x8*)(O + ((size_t)p * NROWS + grow) * 160 + qq * 40 + k * 8);
#pragma unroll
                for (int j = 0; j < 8; j++) sum[j] += (float)x[j];
            }
            bf16x8 hv;
#pragma unroll
            for (int j = 0; j < 8; j++) hv[j] = (__bf16)(sum[j] * inv);
            *(bf16x8*)(HS + rhat * KP + qq * 40 + k * 8) = hv;
        }
    }
    __syncthreads();

    const int m = w & 1, th = w >> 1;
    const int tbase = th ? 3 : 0, tn = th ? 2 : 3;
    f32x16 acc[3];
#pragma unroll
    for (int i = 0; i < 3; i++) acc[i] = z16();

    for (int ch = 0; ch < 2; ch++) {
        const __bf16* src = ch ? HS : AS;
        for (int ks = 0; ks < 10; ks++) {
            bf16x8 af = *(const bf16x8*)(src + (m * 32 + m32) * KP + ks * 16 + half * 8);
#pragma unroll
            for (int ti = 0; ti < 3; ti++) {
                if (ti < tn) {
                    int t = tbase + ti;
                    acc[ti] = __builtin_amdgcn_mfma_f32_32x32x16_bf16(
                        af, *(const bf16x8*)(WtS + (ch * 160 + t * 32 + m32) * KP + ks * 16 + half * 8),
                        acc[ti], 0, 0, 0);
                }
            }
        }
    }

#pragma unroll
    for (int ti = 0; ti < 3; ti++) {
        if (ti < tn) {
            int t = tbase + ti;
            int h = t * 32 + m32;
            if (h < HHH) {
                float bth = bt[h];
#pragma unroll
                for (int r = 0; r < 16; r++) {
                    int rowp = (r & 3) + 8 * (r >> 2) + 4 * half;
                    float v = acc[ti][r] + bth;
                    Out[(size_t)(r0 + m * 32 + rowp) * HHH + h] = v > 0.f ? v : 0.f;
                }
            }
        }
    }
}

// ---------------------------------------------------------------------------
extern "C" void kernel_launch(void* const* d_in, const int* in_sizes, int n_in,
                              void* d_out, int out_size, void* d_ws, size_t ws_size,
                              hipStream_t stream)
{
    const float* Q  = (const float*)d_in[0];
    const float* A  = (const float*)d_in[1];
    const float* Wi = (const float*)d_in[2];
    const float* Wu = (const float*)d_in[3];
    const float* Wg = (const float*)d_in[4];
    const float* Wt = (const float*)d_in[5];
    const float* bi = (const float*)d_in[6];
    const float* bu = (const float*)d_in[7];
    const float* bg = (const float*)d_in[8];
    const float* bt = (const float*)d_in[9];
    float* out = (float*)d_out;

    char* ws = (char*)d_ws;
    __bf16* Slab = (__bf16*)(ws);                    // 11,796,480 B (256 x 46,080)
    __bf16* AhB  = (__bf16*)(ws + 11796480);         //  5,505,024 B
    __bf16* Op   = (__bf16*)(ws + 17301504);         // 20,971,520 B (4 partials)
    float*  Lp   = (float*) (ws + 38273024);         //    262,144 B (4 partials)
    __bf16* WiC  = (__bf16*)(ws + 38535168);         //    131,072 B (4 x 32 KB)
    __bf16* WuC  = (__bf16*)(ws + 38666240);         //    131,072 B
    __bf16* WgT  = (__bf16*)(ws + 38797312);         //     65,536 B (2 x 32 KB)
    __bf16* Wt12 = (__bf16*)(ws + 38862848);         //    107,520 B

    convert_weights<<<dim3(256, 4), 256, 0, stream>>>(Wi, Wu, Wg, Wt,
                                                      WiC, WuC, WgT, Wt12);
    gatep<<<dim3(NROWS / 128, 2), 512, 0, stream>>>(Q, A, WiC, WuC, WgT,
                                                    bi, bu, bg, AhB, Slab);
    attn_mfma<<<dim3(32, 8), 512, 0, stream>>>(Slab, AhB, Op, Lp);
    final_mfma<<<NROWS / 64, 256, 0, stream>>>(AhB, Op, Lp, Wt12, bt, out);
}

// Round 8
// 158.545 us; speedup vs baseline: 1.7704x; 1.0253x over previous
//
#include <hip/hip_runtime.h>
#include <math.h>

#define BB 8
#define LQ 2048
#define DD 300
#define HHH 150
#define NROWS (BB * LQ)

#define KP 168          // row stride (elems) for AhB / Qg / QhA / Wt rows (336 B)
#define QTS 72          // QhT q-stride (144 B)
#define KQ 88           // W chunk row stride (elems, 176 B, 16B-aligned)
#define WCQ 16384       // elems per W chunk slot in GLOBAL layout (32 KB padded)
#define WCE2 14336      // elems per W chunk LDS slot (28,672 B = 28 x 1024)
#define STGW_B 28672    // staged bytes per W chunk — MUST be multiple of 1024
                        // (stage_flat8 stages 1024-B units; 28160 in v6 overran
                        //  512 B into the sibling buffer -> the 0.29 absmax bug)
#define XROW 328        // X-LDS row stride in elems (656 B)
#define SLAB_B 46080    // per-(b,qt) slab bytes (45 KiB, 45 x 1024)
#define SLAB_E 23040    // slab elems; used: Qg 64x168 | QhT @11008 160x72
#define QHT_OFF_E 11008

typedef __bf16 bf16x8 __attribute__((ext_vector_type(8)));
typedef __bf16 bf16x4 __attribute__((ext_vector_type(4)));
typedef float f32x16 __attribute__((ext_vector_type(16)));

__device__ __forceinline__ void gl_lds16(const void* g, void* l) {
    __builtin_amdgcn_global_load_lds(
        (const __attribute__((address_space(1))) void*)g,
        (__attribute__((address_space(3))) void*)l,
        16, 0, 0);
}
// flat async global->LDS copy, 4-wave (256-thr) blocks. bytes % 1024 == 0!
__device__ __forceinline__ void stage_flat(const void* g, void* l, int bytes,
                                           int w, int lane) {
    for (int ofs = w * 1024; ofs < bytes; ofs += 4096)
        gl_lds16((const char*)g + ofs + lane * 16, (char*)l + ofs);
}
// flat async global->LDS copy, 8-wave (512-thr) blocks. bytes % 1024 == 0!
__device__ __forceinline__ void stage_flat8(const void* g, void* l, int bytes,
                                            int w, int lane) {
    for (int ofs = w * 1024; ofs < bytes; ofs += 8192)
        gl_lds16((const char*)g + ofs + lane * 16, (char*)l + ofs);
}
__device__ __forceinline__ f32x16 z16() {
    f32x16 v;
#pragma unroll
    for (int i = 0; i < 16; i++) v[i] = 0.f;
    return v;
}
// pack two f32 -> one u32 of 2 bf16 (no builtin on gfx950; m240)
__device__ __forceinline__ unsigned pk2(float lo, float hi) {
    unsigned d;
    asm("v_cvt_pk_bf16_f32 %0, %1, %2" : "=v"(d) : "v"(lo), "v"(hi));
    return d;
}
// swap a.high-lanes <-> b.low-lanes (v_permlane32_swap_b32 modifies both regs)
__device__ __forceinline__ void pl32(unsigned& a, unsigned& b) {
    asm("v_permlane32_swap_b32 %0, %1" : "+v"(a), "+v"(b));
}
__device__ __forceinline__ bf16x8 mk8(unsigned a, unsigned b, unsigned c, unsigned d) {
    union { unsigned u[4]; bf16x8 v; } x;
    x.u[0] = a; x.u[1] = b; x.u[2] = c; x.u[3] = d;
    return x.v;
}

// ---------------------------------------------------------------------------
// Weight conversion (identical to R5; slots zero-padded through WCQ, which
// the 28,672-B stage reads into its last 512 B — zeros, harmless).
// z=0/1: WiC/WuC [4 chunks][16384] (row h*88 + kc; chunk c: k = c*80 + kc).
// z=2:   WgT     [2 chunks][16384].
// z=3:   Wt12    [2][160][168] (final_mfma layout).
// ---------------------------------------------------------------------------
__global__ __launch_bounds__(256) void convert_weights(
    const float* __restrict__ Wi, const float* __restrict__ Wu,
    const float* __restrict__ Wg, const float* __restrict__ Wt,
    __bf16* __restrict__ WiC, __bf16* __restrict__ WuC,
    __bf16* __restrict__ WgT, __bf16* __restrict__ Wt12)
{
    const int z = blockIdx.y;
    const int i = blockIdx.x * 256 + threadIdx.x;
    if (z < 2) {
        if (i >= 4 * WCQ) return;
        int c = i >> 14, rem = i & (WCQ - 1);
        float v = 0.f;
        if (rem < 160 * KQ) {
            int h = rem / KQ, kc = rem - h * KQ;
            int d = c * 80 + kc;
            if (kc < 80 && d < DD && h < HHH) v = (z ? Wu : Wi)[(size_t)d * HHH + h];
        }
        (z ? WuC : WiC)[i] = (__bf16)v;
    } else if (z == 2) {
        if (i >= 2 * WCQ) return;
        int c = i >> 14, rem = i & (WCQ - 1);
        float v = 0.f;
        if (rem < 160 * KQ) {
            int h = rem / KQ, kc = rem - h * KQ;
            int k = c * 80 + kc;
            if (kc < 80 && k < HHH && h < HHH) v = Wg[(size_t)k * HHH + h];
        }
        WgT[i] = (__bf16)v;
    } else {
        if (i >= 2 * 160 * KP) return;
        int c = i / (160 * KP), rem = i - c * (160 * KP);
        int h = rem / KP, kc = rem - h * KP;
        float v = (kc < HHH && h < HHH) ? Wt[(size_t)(c * HHH + kc) * HHH + h] : 0.f;
        Wt12[i] = (__bf16)v;
    }
}

// ---------------------------------------------------------------------------
// gatep v6c: LINEAR-X restructure + staging-size fix (WCE2/STGW_B 28,672 B).
// Per-block X region (128 rows x 1200 B) is contiguous: stream it with
// lane-consecutive float4 loads (fill-class HBM pattern) -> cvt bf16 -> LDS
// tile XL[128][XROW]. MFMA A-frags then read from LDS. Replaces the
// 32-rows-x-32B strided gather that ran at 1.6 TB/s (v3/v5's real cost).
// Weight phases: chunk p in WB[p&1], stage chunk p+1 at top of phase p
// (1-ahead double buffer, plain __syncthreads). QhA reuses the dead XL
// region for the Qg step. 8 waves: wm=w&3 rows; wn=w>>2 h-tiles {0,1,2|3,4}.
// ---------------------------------------------------------------------------
__global__ __launch_bounds__(512, 2) void gatep(
    const float* __restrict__ Q, const float* __restrict__ A,
    const __bf16* __restrict__ WiC, const __bf16* __restrict__ WuC,
    const __bf16* __restrict__ WgT,
    const float* __restrict__ bi, const float* __restrict__ bu,
    const float* __restrict__ bg,
    __bf16* __restrict__ AhB, __bf16* __restrict__ Slab)
{
    __shared__ __align__(16) __bf16 XL[128 * XROW];  // 83,968 B (X tile / QhA)
    __shared__ __align__(16) __bf16 WB[2][WCE2];     // 57,344 B
    const int tid = threadIdx.x;
    const int w = tid >> 6, lane = tid & 63;
    const int m32 = lane & 31, half = lane >> 5;
    const int wm = w & 3, wn = w >> 2;
    const int tof = wn ? 3 : 0, tn = wn ? 2 : 3;
    const int z = blockIdx.y;
    const int r0 = blockIdx.x * 128;
    const float* X = z ? A : Q;
    const int lim = z ? 8 : 10;     // chunks used (z=1 skips Wg)

#define WSRC(P) (((P) < 8) ? (((P) & 1) ? WuC + ((P) >> 1) * WCQ               \
                                        : WiC + ((P) >> 1) * WCQ)              \
                           : WgT + ((P) - 8) * WCQ)

    // chunk 0 staged first (needed soonest); overlaps the X stream below
    stage_flat8(WSRC(0), WB[0], STGW_B, w, lane);

    // ---- zero the X-LDS pad (cols 300..327), 8-B stores (8-aligned) ----
    {
        const uint2 zz = {0u, 0u};
        for (int idx = tid; idx < 128 * 7; idx += 512) {
            int row = idx / 7, j = idx - row * 7;
            *(uint2*)((char*)XL + row * 656 + 600 + j * 8) = zz;
        }
    }

    // ---- X stream: 9600 float4s, lane-consecutive (linear HBM) ----
    {
        const float4* Xf4 = (const float4*)(X + (size_t)r0 * DD);
        float4 v[19];
#pragma unroll
        for (int i = 0; i < 18; i++) v[i] = Xf4[tid + i * 512];
        const int jt = tid + 9216;
        if (jt < 9600) v[18] = Xf4[jt];
#pragma unroll
        for (int i = 0; i < 18; i++) {
            int j = tid + i * 512;
            int row = j / 75, c4 = j - row * 75;
            unsigned lo = pk2(v[i].x, v[i].y), hi = pk2(v[i].z, v[i].w);
            *(uint2*)((char*)XL + row * 656 + c4 * 8) = (uint2){lo, hi};
        }
        if (jt < 9600) {
            int row = jt / 75, c4 = jt - row * 75;
            unsigned lo = pk2(v[18].x, v[18].y), hi = pk2(v[18].z, v[18].w);
            *(uint2*)((char*)XL + row * 656 + c4 * 8) = (uint2){lo, hi};
        }
    }

    f32x16 ai[3], au[3];
#pragma unroll
    for (int t = 0; t < 3; t++) { ai[t] = z16(); au[t] = z16(); }

    __syncthreads();   // XL content + pad ready; WB0 = chunk 0 landed

    bf16x8 afc[5];
    const int xrow_off = (wm * 32 + m32) * XROW;

#define GPH2(P, ACC, C, RDAF)                                                 \
    {                                                                         \
        if ((P) + 1 < lim) stage_flat8(WSRC((P) + 1), WB[((P) + 1) & 1],      \
                                       STGW_B, w, lane);                      \
        if (RDAF) {                                                           \
            _Pragma("unroll")                                                 \
            for (int ks = 0; ks < 5; ks++)                                    \
                afc[ks] = *(const bf16x8*)(XL + xrow_off + (C) * 80 +         \
                                           ks * 16 + half * 8);               \
        }                                                                     \
        const __bf16* Wb = WB[(P) & 1];                                       \
        _Pragma("unroll")                                                     \
        for (int ks = 0; ks < 5; ks++) {                                      \
            _Pragma("unroll")                                                 \
            for (int ti = 0; ti < 3; ti++)                                    \
                if (ti < tn)                                                  \
                    ACC[ti] = __builtin_amdgcn_mfma_f32_32x32x16_bf16(        \
                        afc[ks],                                              \
                        *(const bf16x8*)(Wb + ((tof + ti) * 32 + m32) * KQ +  \
                                         ks * 16 + half * 8),                 \
                        ACC[ti], 0, 0, 0);                                    \
        }                                                                     \
        __syncthreads();                                                      \
    }

    GPH2(0, ai, 0, 1)
    GPH2(1, au, 0, 0)
    GPH2(2, ai, 1, 1)
    GPH2(3, au, 1, 0)
    GPH2(4, ai, 2, 1)
    GPH2(5, au, 2, 0)
    GPH2(6, ai, 3, 1)
    GPH2(7, au, 3, 0)   // z=0: also staged chunk 8 (Wg s0 -> WB[0])

    // ---- gate epilogue ----
#pragma unroll
    for (int ti = 0; ti < 3; ti++) {
        if (ti >= tn) continue;
        int h = (tof + ti) * 32 + m32;
        int hc = h < HHH ? h : 0;
        float bih = bi[hc], buh = bu[hc];
#pragma unroll
        for (int r = 0; r < 16; r++) {
            float v = 0.f;
            if (h < HHH) {
                float xi = ai[ti][r] + bih, xu = au[ti][r] + buh;
                float s = 1.f / (1.f + __expf(-xi));
                float tt = 1.f - 2.f / (1.f + __expf(2.f * xu));
                v = s * tt;
            }
            ai[ti][r] = v;
        }
    }

    if (z) {  // A-side: write AhB and exit
#pragma unroll
        for (int ti = 0; ti < 3; ti++) {
            if (ti >= tn) continue;
            int h = (tof + ti) * 32 + m32;
#pragma unroll
            for (int r = 0; r < 16; r++) {
                int rowp = (r & 3) + 8 * (r >> 2) + 4 * half;
                AhB[(size_t)(r0 + wm * 32 + rowp) * KP + h] = (__bf16)ai[ti][r];
            }
        }
        return;
    }

    // ---- Q-side: Qh -> QhA (reuses dead XL region; [128][KP]) ----
    __bf16* QhA = XL;
#pragma unroll
    for (int ti = 0; ti < 3; ti++) {
        if (ti >= tn) continue;
        int h = (tof + ti) * 32 + m32;
#pragma unroll
        for (int r = 0; r < 16; r++) {
            int rowp = (r & 3) + 8 * (r >> 2) + 4 * half;
            QhA[(wm * 32 + rowp) * KP + h] = (__bf16)ai[ti][r];
        }
    }
    __syncthreads();   // QhA visible; chunk 8 (WB[0]) landed at phase-7 sync

    stage_flat8(WSRC(9), WB[1], STGW_B, w, lane);   // Wg s1

    bf16x8 afq[2][5];
#pragma unroll
    for (int s = 0; s < 2; s++)
#pragma unroll
        for (int ks = 0; ks < 5; ks++)
            afq[s][ks] = *(const bf16x8*)(QhA + (wm * 32 + m32) * KP +
                                          s * 80 + ks * 16 + half * 8);

    f32x16 qg[3];
#pragma unroll
    for (int t = 0; t < 3; t++) qg[t] = z16();
#pragma unroll
    for (int ks = 0; ks < 5; ks++)
#pragma unroll
        for (int ti = 0; ti < 3; ti++)
            if (ti < tn)
                qg[ti] = __builtin_amdgcn_mfma_f32_32x32x16_bf16(
                    afq[0][ks],
                    *(const bf16x8*)(WB[0] + ((tof + ti) * 32 + m32) * KQ + ks * 16 + half * 8),
                    qg[ti], 0, 0, 0);
    __syncthreads();   // Wg s1 (WB[1]) landed
#pragma unroll
    for (int ks = 0; ks < 5; ks++)
#pragma unroll
        for (int ti = 0; ti < 3; ti++)
            if (ti < tn)
                qg[ti] = __builtin_amdgcn_mfma_f32_32x32x16_bf16(
                    afq[1][ks],
                    *(const bf16x8*)(WB[1] + ((tof + ti) * 32 + m32) * KQ + ks * 16 + half * 8),
                    qg[ti], 0, 0, 0);

    const int b = r0 >> 11, qt0 = (r0 & 2047) >> 6;
#pragma unroll
    for (int ti = 0; ti < 3; ti++) {
        if (ti >= tn) continue;
        int h = (tof + ti) * 32 + m32;
        int hc = h < HHH ? h : 0;
        float bgh = bg[hc];
#pragma unroll
        for (int r = 0; r < 16; r++) {
            int rowp = (r & 3) + 8 * (r >> 2) + 4 * half;
            int q = (r0 & 2047) + wm * 32 + rowp;
            float v = (h < HHH) ? (qg[ti][r] + bgh) : 0.f;
            Slab[(size_t)(b * 32 + (q >> 6)) * SLAB_E + (q & 63) * KP + h] = (__bf16)v;
        }
    }

    // QhT transpose-scatter (512 threads, two 64-q tiles)
    {
        const int jl = tid & 63, tile = (tid >> 6) & 1, hgrp = tid >> 7;
        for (int hseg = hgrp; hseg < 20; hseg += 4) {
            bf16x8 vv = *(const bf16x8*)(QhA + (tile * 64 + jl) * KP + hseg * 8);
            __bf16* dst = Slab + (size_t)(b * 32 + qt0 + tile) * SLAB_E + QHT_OFF_E + jl;
#pragma unroll
            for (int e = 0; e < 8; e++)
                dst[(hseg * 8 + e) * QTS] = vv[e];
        }
    }
}

// ---------------------------------------------------------------------------
// attn v9 (unchanged): T12 in-register P + 3-deep counted-vmcnt pipeline.
// ---------------------------------------------------------------------------
__global__ __launch_bounds__(512, 2) void attn_mfma(
    const __bf16* __restrict__ Slab, const __bf16* __restrict__ AhB,
    __bf16* __restrict__ O, float* __restrict__ L)
{
    __shared__ __align__(16) __bf16 Buf[3][SLAB_E];   // 138,240 B
    const int tid = threadIdx.x;
    const int w = tid >> 6, lane = tid & 63;
    const int m32 = lane & 31, half = lane >> 5;
    const int grp = blockIdx.x;            // 0..31 = b*4 + qp
    const int b = grp >> 2, qp = grp & 3;
    const int a0 = blockIdx.y * 256;

    const char* slabBase = (const char*)Slab + (size_t)(b * 32 + qp * 8) * SLAB_B;
    stage_flat8(slabBase, Buf[0], SLAB_B, w, lane);           // t0: 5-6 loads
    __builtin_amdgcn_sched_barrier(0);

    const __bf16* arow = AhB + (size_t)(b * LQ + a0 + w * 32 + m32) * KP + half * 8;
    bf16x8 af[10];
#pragma unroll
    for (int ks = 0; ks < 10; ks++)
        af[ks] = *(const bf16x8*)(arow + ks * 16);
    __builtin_amdgcn_sched_barrier(0);

    stage_flat8(slabBase + SLAB_B, Buf[1], SLAB_B, w, lane);  // t1
    __builtin_amdgcn_sched_barrier(0);
    asm volatile("s_waitcnt vmcnt(15)" ::: "memory");          // t0 landed
    __builtin_amdgcn_sched_barrier(0);
    __builtin_amdgcn_s_barrier();
    __builtin_amdgcn_sched_barrier(0);

    float lsum = 0.f;
    f32x16 acc[5];
#pragma unroll
    for (int t = 0; t < 5; t++) acc[t] = z16();

    for (int qt = 0; qt < 8; qt++) {
        if (qt < 6)
            stage_flat8(slabBase + (size_t)(qt + 2) * SLAB_B, Buf[(qt + 2) % 3],
                        SLAB_B, w, lane);
        const __bf16* Bq = Buf[qt % 3];
        const __bf16* Bv = Bq + QHT_OFF_E;

        // S^T = Qg(64q rows) x Ah(32a cols), K=160 -> two 32x32 tiles
        f32x16 s0 = z16(), s1 = z16();
        __builtin_amdgcn_s_setprio(1);
        for (int ks = 0; ks < 10; ks++) {
            bf16x8 b0 = *(const bf16x8*)(Bq + m32 * KP + ks * 16 + half * 8);
            bf16x8 b1 = *(const bf16x8*)(Bq + (32 + m32) * KP + ks * 16 + half * 8);
            s0 = __builtin_amdgcn_mfma_f32_32x32x16_bf16(b0, af[ks], s0, 0, 0, 0);
            s1 = __builtin_amdgcn_mfma_f32_32x32x16_bf16(b1, af[ks], s1, 0, 0, 0);
        }
        __builtin_amdgcn_s_setprio(0);

        // P = exp(S) in-register; accumulate l (lane's column a = m32)
#pragma unroll
        for (int r = 0; r < 16; r++) { s0[r] = __expf(s0[r]); lsum += s0[r]; }
#pragma unroll
        for (int r = 0; r < 16; r++) { s1[r] = __expf(s1[r]); lsum += s1[r]; }

        // Build PV B-frags in-register (T12): cvt_pk + permlane32_swap.
        bf16x8 pf[4];
        {
            unsigned w01 = pk2(s0[0], s0[1]),   w45 = pk2(s0[4], s0[5]);
            unsigned w23 = pk2(s0[2], s0[3]),   w67 = pk2(s0[6], s0[7]);
            pl32(w01, w45); pl32(w23, w67);
            pf[0] = mk8(w01, w23, w45, w67);
            unsigned x01 = pk2(s0[8], s0[9]),   x45 = pk2(s0[12], s0[13]);
            unsigned x23 = pk2(s0[10], s0[11]), x67 = pk2(s0[14], s0[15]);
            pl32(x01, x45); pl32(x23, x67);
            pf[1] = mk8(x01, x23, x45, x67);
        }
        {
            unsigned w01 = pk2(s1[0], s1[1]),   w45 = pk2(s1[4], s1[5]);
            unsigned w23 = pk2(s1[2], s1[3]),   w67 = pk2(s1[6], s1[7]);
            pl32(w01, w45); pl32(w23, w67);
            pf[2] = mk8(w01, w23, w45, w67);
            unsigned x01 = pk2(s1[8], s1[9]),   x45 = pk2(s1[12], s1[13]);
            unsigned x23 = pk2(s1[10], s1[11]), x67 = pk2(s1[14], s1[15]);
            pl32(x01, x45); pl32(x23, x67);
            pf[3] = mk8(x01, x23, x45, x67);
        }

        // O^T: acc[t] = QhT(h-rows) x P(a-cols) -> O[a=m32][h = t*32 + rowp]
        __builtin_amdgcn_s_setprio(1);
#pragma unroll
        for (int kk = 0; kk < 4; kk++)
#pragma unroll
            for (int t = 0; t < 5; t++)
                acc[t] = __builtin_amdgcn_mfma_f32_32x32x16_bf16(
                    *(const bf16x8*)(Bv + (t * 32 + m32) * QTS + kk * 16 + half * 8),
                    pf[kk], acc[t], 0, 0, 0);
        __builtin_amdgcn_s_setprio(0);

        if (qt < 7) {
            __builtin_amdgcn_sched_barrier(0);
            if (qt < 6) asm volatile("s_waitcnt vmcnt(5)" ::: "memory");
            else        asm volatile("s_waitcnt vmcnt(0)" ::: "memory");
            __builtin_amdgcn_sched_barrier(0);
            __builtin_amdgcn_s_barrier();
            __builtin_amdgcn_sched_barrier(0);
        }
    }

    // l: this lane has half the q's of column a=m32; partner lane^32 the rest
    float lt = lsum + __shfl_xor(lsum, 32, 64);

    // O store: row a = w*32 + m32; h = t*32 + rq*8 + half*4 + j (contiguous 4)
    __bf16* Ob = O + ((size_t)qp * NROWS + b * LQ + a0 + w * 32) * 160;
#pragma unroll
    for (int t = 0; t < 5; t++)
#pragma unroll
        for (int rq = 0; rq < 4; rq++) {
            bf16x4 hv = {(__bf16)acc[t][rq * 4 + 0], (__bf16)acc[t][rq * 4 + 1],
                         (__bf16)acc[t][rq * 4 + 2], (__bf16)acc[t][rq * 4 + 3]};
            *(bf16x4*)(Ob + (size_t)m32 * 160 + t * 32 + rq * 8 + half * 4) = hv;
        }
    if (half == 0)
        L[(size_t)qp * NROWS + b * LQ + a0 + w * 32 + m32] = lt;
}

// ---------------------------------------------------------------------------
// final (unchanged): Hm = (sum of 4 O partials)/(sum l);
// Out = relu([Ah,Hm]@Wt+bt). Wt staged in LDS (WtS).
// ---------------------------------------------------------------------------
__global__ __launch_bounds__(256, 1) void final_mfma(
    const __bf16* __restrict__ AhB, const __bf16* __restrict__ O,
    const float* __restrict__ L, const __bf16* __restrict__ Wt12,
    const float* __restrict__ bt, float* __restrict__ Out)
{
    __shared__ __align__(16) __bf16 AS[64 * KP];          // 21504 B
    __shared__ __align__(16) __bf16 HS[64 * KP];          // 21504 B
    __shared__ __align__(16) __bf16 WtS[2 * 160 * KP];    // 107520 B
    const int tid = threadIdx.x;
    const int w = tid >> 6, lane = tid & 63;
    const int m32 = lane & 31, half = lane >> 5;
    const int r0 = blockIdx.x * 64;

    stage_flat(AhB + (size_t)r0 * KP, AS, 21504, w, lane);
    stage_flat(Wt12, WtS, 107520, w, lane);

    // combine 4 partials -> HS
    {
        int rhat = tid >> 2, qq = tid & 3;
        int grow = r0 + rhat;
        float inv = 1.f / (L[grow] + L[NROWS + grow] + L[2 * NROWS + grow] + L[3 * NROWS + grow]);
#pragma unroll
        for (int k = 0; k < 5; k++) {
            float sum[8];
#pragma unroll
            for (int j = 0; j < 8; j++) sum[j] = 0.f;
#pragma unroll
            for (int p = 0; p < 4; p++) {
                bf16x8 x = *(const bf16x8*)(O + ((size_t)p * NROWS + grow) * 160 + qq * 40 + k * 8);
#pragma unroll
                for (int j = 0; j < 8; j++) sum[j] += (float)x[j];
            }
            bf16x8 hv;
#pragma unroll
            for (int j = 0; j < 8; j++) hv[j] = (__bf16)(sum[j] * inv);
            *(bf16x8*)(HS + rhat * KP + qq * 40 + k * 8) = hv;
        }
    }
    __syncthreads();

    const int m = w & 1, th = w >> 1;
    const int tbase = th ? 3 : 0, tn = th ? 2 : 3;
    f32x16 acc[3];
#pragma unroll
    for (int i = 0; i < 3; i++) acc[i] = z16();

    for (int ch = 0; ch < 2; ch++) {
        const __bf16* src = ch ? HS : AS;
        for (int ks = 0; ks < 10; ks++) {
            bf16x8 af = *(const bf16x8*)(src + (m * 32 + m32) * KP + ks * 16 + half * 8);
#pragma unroll
            for (int ti = 0; ti < 3; ti++) {
                if (ti < tn) {
                    int t = tbase + ti;
                    acc[ti] = __builtin_amdgcn_mfma_f32_32x32x16_bf16(
                        af, *(const bf16x8*)(WtS + (ch * 160 + t * 32 + m32) * KP + ks * 16 + half * 8),
                        acc[ti], 0, 0, 0);
                }
            }
        }
    }

#pragma unroll
    for (int ti = 0; ti < 3; ti++) {
        if (ti < tn) {
            int t = tbase + ti;
            int h = t * 32 + m32;
            if (h < HHH) {
                float bth = bt[h];
#pragma unroll
                for (int r = 0; r < 16; r++) {
                    int rowp = (r & 3) + 8 * (r >> 2) + 4 * half;
                    float v = acc[ti][r] + bth;
                    Out[(size_t)(r0 + m * 32 + rowp) * HHH + h] = v > 0.f ? v : 0.f;
                }
            }
        }
    }
}

// ---------------------------------------------------------------------------
extern "C" void kernel_launch(void* const* d_in, const int* in_sizes, int n_in,
                              void* d_out, int out_size, void* d_ws, size_t ws_size,
                              hipStream_t stream)
{
    const float* Q  = (const float*)d_in[0];
    const float* A  = (const float*)d_in[1];
    const float* Wi = (const float*)d_in[2];
    const float* Wu = (const float*)d_in[3];
    const float* Wg = (const float*)d_in[4];
    const float* Wt = (const float*)d_in[5];
    const float* bi = (const float*)d_in[6];
    const float* bu = (const float*)d_in[7];
    const float* bg = (const float*)d_in[8];
    const float* bt = (const float*)d_in[9];
    float* out = (float*)d_out;

    char* ws = (char*)d_ws;
    __bf16* Slab = (__bf16*)(ws);                    // 11,796,480 B (256 x 46,080)
    __bf16* AhB  = (__bf16*)(ws + 11796480);         //  5,505,024 B
    __bf16* Op   = (__bf16*)(ws + 17301504);         // 20,971,520 B (4 partials)
    float*  Lp   = (float*) (ws + 38273024);         //    262,144 B (4 partials)
    __bf16* WiC  = (__bf16*)(ws + 38535168);         //    131,072 B (4 x 32 KB)
    __bf16* WuC  = (__bf16*)(ws + 38666240);         //    131,072 B
    __bf16* WgT  = (__bf16*)(ws + 38797312);         //     65,536 B (2 x 32 KB)
    __bf16* Wt12 = (__bf16*)(ws + 38862848);         //    107,520 B

    convert_weights<<<dim3(256, 4), 256, 0, stream>>>(Wi, Wu, Wg, Wt,
                                                      WiC, WuC, WgT, Wt12);
    gatep<<<dim3(NROWS / 128, 2), 512, 0, stream>>>(Q, A, WiC, WuC, WgT,
                                                    bi, bu, bg, AhB, Slab);
    attn_mfma<<<dim3(32, 8), 512, 0, stream>>>(Slab, AhB, Op, Lp);
    final_mfma<<<NROWS / 64, 256, 0, stream>>>(AhB, Op, Lp, Wt12, bt, out);
}